// Round 4
// baseline (482.236 us; speedup 1.0000x reference)
//
#include <hip/hip_runtime.h>
#include <hip/hip_bf16.h>
#include <stdint.h>

#define B_    4
#define QL_   512
#define KVL_  4096
#define QDIM  1024
#define KVDIM 768
#define NCH   1024
#define H_    8
#define DH    128
#define NROWS (B_ * H_ * QL_)   // 16384 partial rows
#define KVBLK 64

typedef unsigned short ushort_t;
typedef __attribute__((ext_vector_type(8))) short bf16x8;
typedef __attribute__((ext_vector_type(4))) float f32x4;
typedef __attribute__((ext_vector_type(4))) unsigned short us4;

__device__ __forceinline__ ushort_t f2bf(float x){
  union { float f; unsigned u; } v; v.f = x;
  unsigned r = v.u + 0x7FFF + ((v.u >> 16) & 1);
  return (ushort_t)(r >> 16);
}

__device__ __forceinline__ void gload16(void* l, const void* g){
  __builtin_amdgcn_global_load_lds(
    (const __attribute__((address_space(1))) unsigned int*)g,
    (__attribute__((address_space(3))) unsigned int*)l, 16, 0, 0);
}

// ---------------- LayerNorm + bf16 cast ----------------
template<int D>
__global__ void ln_kernel(const float* __restrict__ x, const float* __restrict__ gamma,
                          const float* __restrict__ beta, ushort_t* __restrict__ out){
  int row = blockIdx.x;
  const float* xr = x + (size_t)row * D;
  ushort_t* orow = out + (size_t)row * D;
  int tid = threadIdx.x;
  constexpr int NPT = D / 256;
  float v[NPT];
  float s = 0.f, s2 = 0.f;
  #pragma unroll
  for (int k = 0; k < NPT; ++k){ v[k] = xr[tid + k*256]; s += v[k]; s2 += v[k]*v[k]; }
  #pragma unroll
  for (int m = 32; m; m >>= 1){ s += __shfl_xor(s, m); s2 += __shfl_xor(s2, m); }
  __shared__ float red[8];
  int w = tid >> 6;
  if ((tid & 63) == 0){ red[w] = s; red[4 + w] = s2; }
  __syncthreads();
  s  = red[0] + red[1] + red[2] + red[3];
  s2 = red[4] + red[5] + red[6] + red[7];
  float mu  = s / D;
  float var = s2 / D - mu * mu;
  float rs  = rsqrtf(var + 1e-3f);
  #pragma unroll
  for (int k = 0; k < NPT; ++k){
    int i = tid + k*256;
    orow[i] = f2bf((v[k] - mu) * rs * gamma[i] + beta[i]);
  }
}

// ---------------- Weight transpose + bf16 cast: Wt[n][k] = W[k][n] ----------------
__global__ void wtrans_kernel(const float* __restrict__ W, ushort_t* __restrict__ Wt,
                              int K, int N){
  __shared__ float t[32][33];
  int n0 = blockIdx.x * 32, k0 = blockIdx.y * 32;
  int tx = threadIdx.x & 31, ty = threadIdx.x >> 5;   // 32 x 8
  #pragma unroll
  for (int i = 0; i < 32; i += 8) t[ty + i][tx] = W[(size_t)(k0 + ty + i) * N + n0 + tx];
  __syncthreads();
  #pragma unroll
  for (int i = 0; i < 32; i += 8)
    Wt[(size_t)(n0 + ty + i) * K + k0 + tx] = f2bf(t[tx][ty + i]);
}

// ---------------- GEMM: C[m][n] = (sum_k A[m][k]*Bw[n][k] + bias[n]) * oscale ----------------
template<bool TRANSV>
__global__ __launch_bounds__(256)
void gemm_kernel(const ushort_t* __restrict__ A, const ushort_t* __restrict__ Bw,
                 const float* __restrict__ bias, ushort_t* __restrict__ out,
                 int M, int K, float oscale){
  __shared__ __align__(16) ushort_t lds[2][4][128][8];
  int tid = threadIdx.x;
  int w = tid >> 6, lane = tid & 63;
  int m0 = blockIdx.x * 128, n0 = blockIdx.y * 128;
  int wr = w >> 1, wc = w & 1;
  int g = lane >> 4, j = lane & 15;
  f32x4 acc[4][4] = {};
  const int ksteps = K / 32;
  const ushort_t* Aw  = A  + (size_t)(m0 + lane) * K + w * 8;
  const ushort_t* Bww = Bw + (size_t)(n0 + lane) * K + w * 8;
  for (int ks = 0; ks < ksteps; ++ks){
    #pragma unroll
    for (int i = 0; i < 2; ++i){
      gload16(&lds[0][w][i*64][0], Aw  + (size_t)i*64*K + ks*32);
      gload16(&lds[1][w][i*64][0], Bww + (size_t)i*64*K + ks*32);
    }
    __syncthreads();
    bf16x8 af[4], bfr[4];
    #pragma unroll
    for (int mi = 0; mi < 4; ++mi) af[mi]  = *(const bf16x8*)&lds[0][g][wr*64 + mi*16 + j][0];
    #pragma unroll
    for (int ni = 0; ni < 4; ++ni) bfr[ni] = *(const bf16x8*)&lds[1][g][wc*64 + ni*16 + j][0];
    #pragma unroll
    for (int mi = 0; mi < 4; ++mi)
      #pragma unroll
      for (int ni = 0; ni < 4; ++ni)
        acc[mi][ni] = __builtin_amdgcn_mfma_f32_16x16x32_bf16(af[mi], bfr[ni], acc[mi][ni], 0, 0, 0);
    __syncthreads();
  }
  #pragma unroll
  for (int mi = 0; mi < 4; ++mi){
    int row0 = m0 + wr*64 + mi*16 + g*4;
    #pragma unroll
    for (int ni = 0; ni < 4; ++ni){
      int col = n0 + wc*64 + ni*16 + j;
      float bs = bias[col];
      if (!TRANSV){
        #pragma unroll
        for (int r = 0; r < 4; ++r)
          out[(size_t)(row0 + r) * NCH + col] = f2bf((acc[mi][ni][r] + bs) * oscale);
      } else {
        int bidx = row0 >> 12, kv = row0 & (KVL_ - 1);
        int h = col >> 7, dv = col & 127;
        us4 pk;
        #pragma unroll
        for (int r = 0; r < 4; ++r) pk[r] = f2bf(acc[mi][ni][r] + bs);
        *(us4*)&out[((size_t)(bidx * H_ + h) * DH + dv) * KVL_ + kv] = pk;
      }
    }
  }
}

// ---------------- Flash attention: 8-wave block, LDS-staged K/V, KV-split ----------------
// Q is pre-scaled by (1/sqrt(DH))*log2(e): scores in log2 domain.
// grid = 64*NS. bid = xcd + 8*slot; p = xcd + 8*(slot>>1) -> (bh, sp); qb = slot&1.
template<int NS>
__global__ __launch_bounds__(512, 4)
void attn_kernel(const ushort_t* __restrict__ Q, const ushort_t* __restrict__ Km,
                 const ushort_t* __restrict__ Vt, float* __restrict__ ctxp,
                 float* __restrict__ mlp){
  __shared__ __align__(16) ushort_t Kbuf[2][KVBLK][DH];   // 32 KB
  __shared__ __align__(16) ushort_t Vbuf[2][DH][KVBLK];   // 32 KB
  __shared__ __align__(16) ushort_t plds[8][16][64];      // 16 KB (XOR-swizzled)

  int bid = blockIdx.x;
  int xcd = bid & 7, slot = bid >> 3;
  int p   = xcd + 8 * (slot >> 1);
  int qb  = slot & 1;
  int bh  = p / NS, sp = p % NS;
  int b = bh >> 3, h = bh & 7;

  int tid = threadIdx.x;
  int w = tid >> 6, lane = tid & 63;
  int g = lane >> 4, j = lane & 15;
  int qbase = qb * 256 + w * 32;          // wave's 32 q-rows

  bf16x8 qreg[2][4];
  #pragma unroll
  for (int qf = 0; qf < 2; ++qf){
    const ushort_t* Qb = Q + (size_t)(b * QL_ + qbase + qf * 16 + j) * NCH + h * DH + g * 8;
    #pragma unroll
    for (int kb = 0; kb < 4; ++kb) qreg[qf][kb] = *(const bf16x8*)(Qb + kb * 32);
  }

  f32x4 ctx[2][8] = {};
  float m_[2][4], l_[2][4];
  #pragma unroll
  for (int qf = 0; qf < 2; ++qf)
    #pragma unroll
    for (int r = 0; r < 4; ++r){ m_[qf][r] = -1e30f; l_[qf][r] = 0.f; }

  const int kvbeg = sp * (KVL_ / NS);
  const char* Kg = (const char*)(Km + (size_t)b * KVL_ * NCH) + h * 256;
  const char* Vg = (const char*)(Vt + (size_t)(b * H_ + h) * DH * KVL_);

  auto stage = [&](int bi, int kv0){
    #pragma unroll
    for (int i = 0; i < 2; ++i){
      int lin = (i * 512 + tid) * 16;
      int sw  = lin ^ (((lin >> 8) & 7) << 4);
      gload16((char*)&Kbuf[bi][0][0] + lin,
              Kg + (size_t)(kv0 + (sw >> 8)) * 2048 + (sw & 255));
    }
    #pragma unroll
    for (int i = 0; i < 2; ++i){
      int lin = (i * 512 + tid) * 16;
      int sw  = lin ^ (((lin >> 7) & 7) << 4);
      gload16((char*)&Vbuf[bi][0][0] + lin,
              Vg + (size_t)(sw >> 7) * (KVL_ * 2) + kv0 * 2 + (sw & 127));
    }
  };

  char* mypb = (char*)&plds[w][0][0];
  const float THR = 11.5415603f;            // 8 * log2(e)
  const int NCHUNK = (KVL_ / NS) / KVBLK;

  stage(0, kvbeg);
  __syncthreads();

  for (int c = 0; c < NCHUNK; ++c){
    int bi = c & 1;
    if (c + 1 < NCHUNK) stage(bi ^ 1, kvbeg + (c + 1) * KVBLK);

    const char* Kl = (const char*)&Kbuf[bi][0][0];
    const char* Vl = (const char*)&Vbuf[bi][0][0];
    bf16x8 pa[2][2];

    #pragma unroll
    for (int qf = 0; qf < 2; ++qf){
      f32x4 s[4] = {};
      __builtin_amdgcn_s_setprio(1);
      #pragma unroll
      for (int kf = 0; kf < 4; ++kf){
        #pragma unroll
        for (int kb = 0; kb < 4; ++kb){
          int off = (kf * 16 + j) * 256 + kb * 64 + g * 16;
          off ^= ((j & 7) << 4);
          s[kf] = __builtin_amdgcn_mfma_f32_16x16x32_bf16(
                    qreg[qf][kb], *(const bf16x8*)(Kl + off), s[kf], 0, 0, 0);
        }
      }
      __builtin_amdgcn_s_setprio(0);
      // online softmax (log2 domain), defer-max
      float pm[4];
      #pragma unroll
      for (int r = 0; r < 4; ++r){
        pm[r] = fmaxf(fmaxf(s[0][r], s[1][r]), fmaxf(s[2][r], s[3][r]));
        #pragma unroll
        for (int msk = 1; msk < 16; msk <<= 1) pm[r] = fmaxf(pm[r], __shfl_xor(pm[r], msk));
      }
      int ok = 1;
      #pragma unroll
      for (int r = 0; r < 4; ++r) ok &= (pm[r] - m_[qf][r] <= THR);
      if (!__all(ok)){
        float cf[4];
        #pragma unroll
        for (int r = 0; r < 4; ++r){
          float mn = fmaxf(m_[qf][r], pm[r]);
          cf[r] = exp2f(m_[qf][r] - mn);
          m_[qf][r] = mn;
          l_[qf][r] *= cf[r];
        }
        #pragma unroll
        for (int df = 0; df < 8; ++df)
          #pragma unroll
          for (int r = 0; r < 4; ++r) ctx[qf][df][r] *= cf[r];
      }
      #pragma unroll
      for (int r = 0; r < 4; ++r){
        float rs_ = 0.f;
        #pragma unroll
        for (int kf = 0; kf < 4; ++kf){ s[kf][r] = exp2f(s[kf][r] - m_[qf][r]); rs_ += s[kf][r]; }
        #pragma unroll
        for (int msk = 1; msk < 16; msk <<= 1) rs_ += __shfl_xor(rs_, msk);
        l_[qf][r] += rs_;
      }
      // P -> per-wave swizzled LDS tile (row = q 0..15, col = kv 0..63)
      #pragma unroll
      for (int kf = 0; kf < 4; ++kf)
        #pragma unroll
        for (int r = 0; r < 4; ++r){
          int row = g * 4 + r;
          int wb = row * 128 + (kf * 16 + j) * 2;
          wb ^= ((row >> 1) & 7) << 4;
          *(ushort_t*)(mypb + wb) = f2bf(s[kf][r]);
        }
      {
        int rb0 = j * 128 + g * 16;        rb0 ^= ((j >> 1) & 7) << 4;
        int rb1 = j * 128 + 64 + g * 16;   rb1 ^= ((j >> 1) & 7) << 4;
        pa[qf][0] = *(const bf16x8*)(mypb + rb0);
        pa[qf][1] = *(const bf16x8*)(mypb + rb1);
      }
    }

    // PV
    __builtin_amdgcn_s_setprio(1);
    #pragma unroll
    for (int df = 0; df < 8; ++df){
      #pragma unroll
      for (int kc = 0; kc < 2; ++kc){
        int off = (df * 16 + j) * 128 + kc * 64 + g * 16;
        off ^= ((j & 7) << 4);
        bf16x8 vf = *(const bf16x8*)(Vl + off);
        ctx[0][df] = __builtin_amdgcn_mfma_f32_16x16x32_bf16(pa[0][kc], vf, ctx[0][df], 0, 0, 0);
        ctx[1][df] = __builtin_amdgcn_mfma_f32_16x16x32_bf16(pa[1][kc], vf, ctx[1][df], 0, 0, 0);
      }
    }
    __builtin_amdgcn_s_setprio(0);
    __syncthreads();
  }

  size_t prow0 = ((size_t)sp * 32 + bh) * QL_ + qbase;
  #pragma unroll
  for (int qf = 0; qf < 2; ++qf){
    #pragma unroll
    for (int r = 0; r < 4; ++r){
      float* cp = ctxp + (prow0 + qf * 16 + g * 4 + r) * DH;
      #pragma unroll
      for (int df = 0; df < 8; ++df) cp[df * 16 + j] = ctx[qf][df][r];
    }
    if (j == 0){
      #pragma unroll
      for (int r = 0; r < 4; ++r){
        size_t pr = prow0 + qf * 16 + g * 4 + r;
        mlp[pr * 2]     = m_[qf][r];
        mlp[pr * 2 + 1] = l_[qf][r];
      }
    }
  }
}

// ---------------- Split combine: 1 wave per q-row (m in log2 domain) ----------------
template<int NS>
__global__ __launch_bounds__(256)
void combine_kernel(const float* __restrict__ ctxp, const float* __restrict__ mlp,
                    float* __restrict__ out){
  int row = blockIdx.x * 4 + (threadIdx.x >> 6);   // (b*8+h)*512 + q
  int lane = threadIdx.x & 63;
  int b = row >> 12, h = (row >> 9) & 7, q = row & 511;
  float ms[NS], ls[NS];
  #pragma unroll
  for (int s = 0; s < NS; ++s){
    ms[s] = mlp[((size_t)(s * NROWS + row)) * 2];
    ls[s] = mlp[((size_t)(s * NROWS + row)) * 2 + 1];
  }
  float M = ms[0];
  #pragma unroll
  for (int s = 1; s < NS; ++s) M = fmaxf(M, ms[s]);
  float wgt[NS], L = 0.f;
  #pragma unroll
  for (int s = 0; s < NS; ++s){ wgt[s] = exp2f(ms[s] - M); L += ls[s] * wgt[s]; }
  float inv = 1.f / L;
  float ax = 0.f, ay = 0.f;
  #pragma unroll
  for (int s = 0; s < NS; ++s){
    const float* cp = ctxp + ((size_t)(s * NROWS + row)) * DH + lane * 2;
    ax += cp[0] * wgt[s]; ay += cp[1] * wgt[s];
  }
  float* op = out + ((size_t)(b * QL_ + q)) * NCH + h * DH + lane * 2;
  op[0] = ax * inv; op[1] = ay * inv;
}

extern "C" void kernel_launch(void* const* d_in, const int* in_sizes, int n_in,
                              void* d_out, int out_size, void* d_ws, size_t ws_size,
                              hipStream_t stream){
  const float* hs   = (const float*)d_in[0];
  const float* inp  = (const float*)d_in[1];
  const float* ln1g = (const float*)d_in[2];
  const float* ln1b = (const float*)d_in[3];
  const float* ln2g = (const float*)d_in[4];
  const float* ln2b = (const float*)d_in[5];
  const float* Wq   = (const float*)d_in[6];
  const float* bq   = (const float*)d_in[7];
  const float* Wk   = (const float*)d_in[8];
  const float* bk   = (const float*)d_in[9];
  const float* Wv   = (const float*)d_in[10];
  const float* bv   = (const float*)d_in[11];

  char* ws = (char*)d_ws;
  size_t off = 0;
  auto alloc = [&](size_t bytes){ void* pp = ws + off; off += (bytes + 255) & ~255ull; return pp; };
  // persistent across phases
  ushort_t* Qm = (ushort_t*)alloc((size_t)2048 * 1024 * 2);
  ushort_t* Km = (ushort_t*)alloc((size_t)16384 * 1024 * 2);
  ushort_t* Vt = (ushort_t*)alloc((size_t)16384 * 1024 * 2);
  size_t base2 = off;
  // phase 1: LN outputs + transposed weights (dead after the GEMMs)
  ushort_t* hs_ln = (ushort_t*)alloc((size_t)2048 * 1024 * 2);
  ushort_t* in_ln = (ushort_t*)alloc((size_t)16384 * 768 * 2);
  ushort_t* Wqt   = (ushort_t*)alloc((size_t)1024 * 1024 * 2);
  ushort_t* Wkt   = (ushort_t*)alloc((size_t)1024 * 768 * 2);
  ushort_t* Wvt   = (ushort_t*)alloc((size_t)1024 * 768 * 2);
  // phase 2: attention partials (alias phase 1) — NS chosen by ws budget
  size_t need8 = base2 + ((size_t)8 * NROWS * DH * 4 + 256) + ((size_t)8 * NROWS * 2 * 4 + 256);
  int NS = (ws_size >= need8) ? 8 : 4;
  off = base2;
  float* ctxp = (float*)alloc((size_t)NS * NROWS * DH * 4);
  float* mlp  = (float*)alloc((size_t)NS * NROWS * 2 * 4);

  const float QSC = 0.08838834764831845f * 1.4426950408889634f;  // 1/sqrt(128)*log2(e)

  ln_kernel<1024><<<2048, 256, 0, stream>>>(hs, ln1g, ln1b, hs_ln);
  ln_kernel<768><<<16384, 256, 0, stream>>>(inp, ln2g, ln2b, in_ln);
  wtrans_kernel<<<dim3(32, 32), 256, 0, stream>>>(Wq, Wqt, 1024, 1024);
  wtrans_kernel<<<dim3(32, 24), 256, 0, stream>>>(Wk, Wkt, 768, 1024);
  wtrans_kernel<<<dim3(32, 24), 256, 0, stream>>>(Wv, Wvt, 768, 1024);
  gemm_kernel<false><<<dim3(16, 8),  256, 0, stream>>>(hs_ln, Wqt, bq, Qm, 2048, 1024, QSC);
  gemm_kernel<false><<<dim3(128, 8), 256, 0, stream>>>(in_ln, Wkt, bk, Km, 16384, 768, 1.0f);
  gemm_kernel<true ><<<dim3(128, 8), 256, 0, stream>>>(in_ln, Wvt, bv, Vt, 16384, 768, 1.0f);
  if (NS == 8){
    attn_kernel<8><<<512, 512, 0, stream>>>(Qm, Km, Vt, ctxp, mlp);
    combine_kernel<8><<<NROWS / 4, 256, 0, stream>>>(ctxp, mlp, (float*)d_out);
  } else {
    attn_kernel<4><<<256, 512, 0, stream>>>(Qm, Km, Vt, ctxp, mlp);
    combine_kernel<4><<<NROWS / 4, 256, 0, stream>>>(ctxp, mlp, (float*)d_out);
  }
}

// Round 5
// 323.394 us; speedup vs baseline: 1.4912x; 1.4912x over previous
//
#include <hip/hip_runtime.h>
#include <hip/hip_bf16.h>
#include <stdint.h>

#define B_    4
#define QL_   512
#define KVL_  4096
#define QDIM  1024
#define KVDIM 768
#define NCH   1024
#define H_    8
#define DH    128
#define NROWS (B_ * H_ * QL_)   // 16384 partial rows
#define KVBLK 64
#define NS    4

typedef unsigned short ushort_t;
typedef __attribute__((ext_vector_type(8))) short bf16x8;
typedef __attribute__((ext_vector_type(4))) float f32x4;
typedef __attribute__((ext_vector_type(4))) unsigned short us4;

__device__ __forceinline__ ushort_t f2bf(float x){
  union { float f; unsigned u; } v; v.f = x;
  unsigned r = v.u + 0x7FFF + ((v.u >> 16) & 1);
  return (ushort_t)(r >> 16);
}

__device__ __forceinline__ void gload16(void* l, const void* g){
  __builtin_amdgcn_global_load_lds(
    (const __attribute__((address_space(1))) unsigned int*)g,
    (__attribute__((address_space(3))) unsigned int*)l, 16, 0, 0);
}

// ---------------- LayerNorm + bf16 cast ----------------
template<int D>
__global__ void ln_kernel(const float* __restrict__ x, const float* __restrict__ gamma,
                          const float* __restrict__ beta, ushort_t* __restrict__ out){
  int row = blockIdx.x;
  const float* xr = x + (size_t)row * D;
  ushort_t* orow = out + (size_t)row * D;
  int tid = threadIdx.x;
  constexpr int NPT = D / 256;
  float v[NPT];
  float s = 0.f, s2 = 0.f;
  #pragma unroll
  for (int k = 0; k < NPT; ++k){ v[k] = xr[tid + k*256]; s += v[k]; s2 += v[k]*v[k]; }
  #pragma unroll
  for (int m = 32; m; m >>= 1){ s += __shfl_xor(s, m); s2 += __shfl_xor(s2, m); }
  __shared__ float red[8];
  int w = tid >> 6;
  if ((tid & 63) == 0){ red[w] = s; red[4 + w] = s2; }
  __syncthreads();
  s  = red[0] + red[1] + red[2] + red[3];
  s2 = red[4] + red[5] + red[6] + red[7];
  float mu  = s / D;
  float var = s2 / D - mu * mu;
  float rs  = rsqrtf(var + 1e-3f);
  #pragma unroll
  for (int k = 0; k < NPT; ++k){
    int i = tid + k*256;
    orow[i] = f2bf((v[k] - mu) * rs * gamma[i] + beta[i]);
  }
}

// ---------------- Weight transpose + bf16 cast: Wt[n][k] = W[k][n] ----------------
__global__ void wtrans_kernel(const float* __restrict__ W, ushort_t* __restrict__ Wt,
                              int K, int N){
  __shared__ float t[32][33];
  int n0 = blockIdx.x * 32, k0 = blockIdx.y * 32;
  int tx = threadIdx.x & 31, ty = threadIdx.x >> 5;   // 32 x 8
  #pragma unroll
  for (int i = 0; i < 32; i += 8) t[ty + i][tx] = W[(size_t)(k0 + ty + i) * N + n0 + tx];
  __syncthreads();
  #pragma unroll
  for (int i = 0; i < 32; i += 8)
    Wt[(size_t)(n0 + ty + i) * K + k0 + tx] = f2bf(t[tx][ty + i]);
}

// ---------------- GEMM: C[m][n] = (sum_k A[m][k]*Bw[n][k] + bias[n]) * oscale ----------------
template<bool TRANSV>
__global__ __launch_bounds__(256)
void gemm_kernel(const ushort_t* __restrict__ A, const ushort_t* __restrict__ Bw,
                 const float* __restrict__ bias, ushort_t* __restrict__ out,
                 int M, int K, float oscale){
  __shared__ __align__(16) ushort_t lds[2][4][128][8];
  int tid = threadIdx.x;
  int w = tid >> 6, lane = tid & 63;
  int m0 = blockIdx.x * 128, n0 = blockIdx.y * 128;
  int wr = w >> 1, wc = w & 1;
  int g = lane >> 4, j = lane & 15;
  f32x4 acc[4][4] = {};
  const int ksteps = K / 32;
  const ushort_t* Aw  = A  + (size_t)(m0 + lane) * K + w * 8;
  const ushort_t* Bww = Bw + (size_t)(n0 + lane) * K + w * 8;
  for (int ks = 0; ks < ksteps; ++ks){
    #pragma unroll
    for (int i = 0; i < 2; ++i){
      gload16(&lds[0][w][i*64][0], Aw  + (size_t)i*64*K + ks*32);
      gload16(&lds[1][w][i*64][0], Bww + (size_t)i*64*K + ks*32);
    }
    __syncthreads();
    bf16x8 af[4], bfr[4];
    #pragma unroll
    for (int mi = 0; mi < 4; ++mi) af[mi]  = *(const bf16x8*)&lds[0][g][wr*64 + mi*16 + j][0];
    #pragma unroll
    for (int ni = 0; ni < 4; ++ni) bfr[ni] = *(const bf16x8*)&lds[1][g][wc*64 + ni*16 + j][0];
    #pragma unroll
    for (int mi = 0; mi < 4; ++mi)
      #pragma unroll
      for (int ni = 0; ni < 4; ++ni)
        acc[mi][ni] = __builtin_amdgcn_mfma_f32_16x16x32_bf16(af[mi], bfr[ni], acc[mi][ni], 0, 0, 0);
    __syncthreads();
  }
  #pragma unroll
  for (int mi = 0; mi < 4; ++mi){
    int row0 = m0 + wr*64 + mi*16 + g*4;
    #pragma unroll
    for (int ni = 0; ni < 4; ++ni){
      int col = n0 + wc*64 + ni*16 + j;
      float bs = bias[col];
      if (!TRANSV){
        #pragma unroll
        for (int r = 0; r < 4; ++r)
          out[(size_t)(row0 + r) * NCH + col] = f2bf((acc[mi][ni][r] + bs) * oscale);
      } else {
        int bidx = row0 >> 12, kv = row0 & (KVL_ - 1);
        int h = col >> 7, dv = col & 127;
        us4 pk;
        #pragma unroll
        for (int r = 0; r < 4; ++r) pk[r] = f2bf(acc[mi][ni][r] + bs);
        *(us4*)&out[((size_t)(bidx * H_ + h) * DH + dv) * KVL_ + kv] = pk;
      }
    }
  }
}

// ---------------- Flash attention: 8-wave block, 16 q-rows/wave, LDS-staged K/V ----------------
// Q pre-scaled by (1/sqrt(DH))*log2(e): scores in log2 domain.
// grid = 512. bid = xcd + 8*slot; p = xcd + 8*(slot>>2) -> (bh, sp); qb = slot&3.
__global__ __launch_bounds__(512, 4)
void attn_kernel(const ushort_t* __restrict__ Q, const ushort_t* __restrict__ Km,
                 const ushort_t* __restrict__ Vt, float* __restrict__ ctxp,
                 float* __restrict__ mlp){
  __shared__ __align__(16) ushort_t Kbuf[2][KVBLK][DH];   // 32 KB
  __shared__ __align__(16) ushort_t Vbuf[2][DH][KVBLK];   // 32 KB
  __shared__ __align__(16) ushort_t plds[8][16][64];      // 16 KB (XOR-swizzled)

  int bid = blockIdx.x;
  int xcd = bid & 7, slot = bid >> 3;
  int p   = xcd + 8 * (slot >> 2);       // 0..127 -> (bh, sp)
  int qb  = slot & 3;
  int bh  = p >> 2, sp = p & 3;
  int b = bh >> 3, h = bh & 7;

  int tid = threadIdx.x;
  int w = tid >> 6, lane = tid & 63;
  int g = lane >> 4, j = lane & 15;
  int qbase = qb * 128 + w * 16;          // wave's 16 q-rows

  bf16x8 qreg[4];
  {
    const ushort_t* Qb = Q + (size_t)(b * QL_ + qbase + j) * NCH + h * DH + g * 8;
    #pragma unroll
    for (int kb = 0; kb < 4; ++kb) qreg[kb] = *(const bf16x8*)(Qb + kb * 32);
  }

  f32x4 ctx[8] = {};
  float m_[4], l_[4];
  #pragma unroll
  for (int r = 0; r < 4; ++r){ m_[r] = -1e30f; l_[r] = 0.f; }

  const int kvbeg = sp * (KVL_ / NS);
  const char* Kg = (const char*)(Km + (size_t)b * KVL_ * NCH) + h * 256;
  const char* Vg = (const char*)(Vt + (size_t)(b * H_ + h) * DH * KVL_);

  auto stage = [&](int bi, int kv0){
    #pragma unroll
    for (int i = 0; i < 2; ++i){
      int lin = (i * 512 + tid) * 16;
      int sw  = lin ^ (((lin >> 8) & 7) << 4);
      gload16((char*)&Kbuf[bi][0][0] + lin,
              Kg + (size_t)(kv0 + (sw >> 8)) * 2048 + (sw & 255));
    }
    #pragma unroll
    for (int i = 0; i < 2; ++i){
      int lin = (i * 512 + tid) * 16;
      int sw  = lin ^ (((lin >> 7) & 7) << 4);
      gload16((char*)&Vbuf[bi][0][0] + lin,
              Vg + (size_t)(sw >> 7) * (KVL_ * 2) + kv0 * 2 + (sw & 127));
    }
  };

  char* mypb = (char*)&plds[w][0][0];
  const float THR = 11.5415603f;            // 8 * log2(e)
  const int NCHUNK = (KVL_ / NS) / KVBLK;   // 16

  stage(0, kvbeg);
  __syncthreads();

  for (int c = 0; c < NCHUNK; ++c){
    int bi = c & 1;
    if (c + 1 < NCHUNK) stage(bi ^ 1, kvbeg + (c + 1) * KVBLK);

    const char* Kl = (const char*)&Kbuf[bi][0][0];
    const char* Vl = (const char*)&Vbuf[bi][0][0];

    f32x4 s[4] = {};
    __builtin_amdgcn_s_setprio(1);
    #pragma unroll
    for (int kf = 0; kf < 4; ++kf){
      #pragma unroll
      for (int kb = 0; kb < 4; ++kb){
        int off = (kf * 16 + j) * 256 + kb * 64 + g * 16;
        off ^= ((j & 7) << 4);
        s[kf] = __builtin_amdgcn_mfma_f32_16x16x32_bf16(
                  qreg[kb], *(const bf16x8*)(Kl + off), s[kf], 0, 0, 0);
      }
    }
    __builtin_amdgcn_s_setprio(0);

    // online softmax (log2 domain), defer-max
    float pm[4];
    #pragma unroll
    for (int r = 0; r < 4; ++r){
      pm[r] = fmaxf(fmaxf(s[0][r], s[1][r]), fmaxf(s[2][r], s[3][r]));
      #pragma unroll
      for (int msk = 1; msk < 16; msk <<= 1) pm[r] = fmaxf(pm[r], __shfl_xor(pm[r], msk));
    }
    int ok = 1;
    #pragma unroll
    for (int r = 0; r < 4; ++r) ok &= (pm[r] - m_[r] <= THR);
    if (!__all(ok)){
      float cf[4];
      #pragma unroll
      for (int r = 0; r < 4; ++r){
        float mn = fmaxf(m_[r], pm[r]);
        cf[r] = exp2f(m_[r] - mn);
        m_[r] = mn;
        l_[r] *= cf[r];
      }
      #pragma unroll
      for (int df = 0; df < 8; ++df)
        #pragma unroll
        for (int r = 0; r < 4; ++r) ctx[df][r] *= cf[r];
    }
    #pragma unroll
    for (int r = 0; r < 4; ++r){
      float rs_ = 0.f;
      #pragma unroll
      for (int kf = 0; kf < 4; ++kf){ s[kf][r] = exp2f(s[kf][r] - m_[r]); rs_ += s[kf][r]; }
      #pragma unroll
      for (int msk = 1; msk < 16; msk <<= 1) rs_ += __shfl_xor(rs_, msk);
      l_[r] += rs_;
    }
    // P -> per-wave swizzled LDS tile (row = q 0..15, col = kv 0..63)
    #pragma unroll
    for (int kf = 0; kf < 4; ++kf)
      #pragma unroll
      for (int r = 0; r < 4; ++r){
        int row = g * 4 + r;
        int wb = row * 128 + (kf * 16 + j) * 2;
        wb ^= ((row >> 1) & 7) << 4;
        *(ushort_t*)(mypb + wb) = f2bf(s[kf][r]);
      }
    bf16x8 pa0, pa1;
    {
      int rb0 = j * 128 + g * 16;        rb0 ^= ((j >> 1) & 7) << 4;
      int rb1 = j * 128 + 64 + g * 16;   rb1 ^= ((j >> 1) & 7) << 4;
      pa0 = *(const bf16x8*)(mypb + rb0);
      pa1 = *(const bf16x8*)(mypb + rb1);
    }

    // PV
    __builtin_amdgcn_s_setprio(1);
    #pragma unroll
    for (int df = 0; df < 8; ++df){
      int off0 = (df * 16 + j) * 128 + g * 16;        int o0 = off0 ^ ((j & 7) << 4);
      int off1 = (df * 16 + j) * 128 + 64 + g * 16;   int o1 = off1 ^ ((j & 7) << 4);
      ctx[df] = __builtin_amdgcn_mfma_f32_16x16x32_bf16(pa0, *(const bf16x8*)(Vl + o0), ctx[df], 0, 0, 0);
      ctx[df] = __builtin_amdgcn_mfma_f32_16x16x32_bf16(pa1, *(const bf16x8*)(Vl + o1), ctx[df], 0, 0, 0);
    }
    __builtin_amdgcn_s_setprio(0);
    __syncthreads();
  }

  size_t prow0 = ((size_t)sp * 32 + bh) * QL_ + qbase;
  #pragma unroll
  for (int r = 0; r < 4; ++r){
    float* cp = ctxp + (prow0 + g * 4 + r) * DH;
    #pragma unroll
    for (int df = 0; df < 8; ++df) cp[df * 16 + j] = ctx[df][r];
  }
  if (j == 0){
    #pragma unroll
    for (int r = 0; r < 4; ++r){
      size_t pr = prow0 + g * 4 + r;
      mlp[pr * 2]     = m_[r];
      mlp[pr * 2 + 1] = l_[r];
    }
  }
}

// ---------------- Split combine: 1 wave per q-row (m in log2 domain) ----------------
__global__ __launch_bounds__(256)
void combine_kernel(const float* __restrict__ ctxp, const float* __restrict__ mlp,
                    float* __restrict__ out){
  int row = blockIdx.x * 4 + (threadIdx.x >> 6);   // (b*8+h)*512 + q
  int lane = threadIdx.x & 63;
  int b = row >> 12, h = (row >> 9) & 7, q = row & 511;
  float ms[NS], ls[NS];
  #pragma unroll
  for (int s = 0; s < NS; ++s){
    ms[s] = mlp[((size_t)(s * NROWS + row)) * 2];
    ls[s] = mlp[((size_t)(s * NROWS + row)) * 2 + 1];
  }
  float M = ms[0];
  #pragma unroll
  for (int s = 1; s < NS; ++s) M = fmaxf(M, ms[s]);
  float wgt[NS], L = 0.f;
  #pragma unroll
  for (int s = 0; s < NS; ++s){ wgt[s] = exp2f(ms[s] - M); L += ls[s] * wgt[s]; }
  float inv = 1.f / L;
  float ax = 0.f, ay = 0.f;
  #pragma unroll
  for (int s = 0; s < NS; ++s){
    const float* cp = ctxp + ((size_t)(s * NROWS + row)) * DH + lane * 2;
    ax += cp[0] * wgt[s]; ay += cp[1] * wgt[s];
  }
  float* op = out + ((size_t)(b * QL_ + q)) * NCH + h * DH + lane * 2;
  op[0] = ax * inv; op[1] = ay * inv;
}

extern "C" void kernel_launch(void* const* d_in, const int* in_sizes, int n_in,
                              void* d_out, int out_size, void* d_ws, size_t ws_size,
                              hipStream_t stream){
  const float* hs   = (const float*)d_in[0];
  const float* inp  = (const float*)d_in[1];
  const float* ln1g = (const float*)d_in[2];
  const float* ln1b = (const float*)d_in[3];
  const float* ln2g = (const float*)d_in[4];
  const float* ln2b = (const float*)d_in[5];
  const float* Wq   = (const float*)d_in[6];
  const float* bq   = (const float*)d_in[7];
  const float* Wk   = (const float*)d_in[8];
  const float* bk   = (const float*)d_in[9];
  const float* Wv   = (const float*)d_in[10];
  const float* bv   = (const float*)d_in[11];

  char* ws = (char*)d_ws;
  size_t off = 0;
  auto alloc = [&](size_t bytes){ void* pp = ws + off; off += (bytes + 255) & ~255ull; return pp; };
  // persistent across phases
  ushort_t* Qm = (ushort_t*)alloc((size_t)2048 * 1024 * 2);
  ushort_t* Km = (ushort_t*)alloc((size_t)16384 * 1024 * 2);
  ushort_t* Vt = (ushort_t*)alloc((size_t)16384 * 1024 * 2);
  size_t base2 = off;
  // phase 1: LN outputs + transposed weights (dead after the GEMMs)
  ushort_t* hs_ln = (ushort_t*)alloc((size_t)2048 * 1024 * 2);
  ushort_t* in_ln = (ushort_t*)alloc((size_t)16384 * 768 * 2);
  ushort_t* Wqt   = (ushort_t*)alloc((size_t)1024 * 1024 * 2);
  ushort_t* Wkt   = (ushort_t*)alloc((size_t)1024 * 768 * 2);
  ushort_t* Wvt   = (ushort_t*)alloc((size_t)1024 * 768 * 2);
  // phase 2: attention partials (alias phase 1)
  off = base2;
  float* ctxp = (float*)alloc((size_t)NS * NROWS * DH * 4);
  float* mlp  = (float*)alloc((size_t)NS * NROWS * 2 * 4);

  const float QSC = 0.08838834764831845f * 1.4426950408889634f;  // 1/sqrt(128)*log2(e)

  ln_kernel<1024><<<2048, 256, 0, stream>>>(hs, ln1g, ln1b, hs_ln);
  ln_kernel<768><<<16384, 256, 0, stream>>>(inp, ln2g, ln2b, in_ln);
  wtrans_kernel<<<dim3(32, 32), 256, 0, stream>>>(Wq, Wqt, 1024, 1024);
  wtrans_kernel<<<dim3(32, 24), 256, 0, stream>>>(Wk, Wkt, 768, 1024);
  wtrans_kernel<<<dim3(32, 24), 256, 0, stream>>>(Wv, Wvt, 768, 1024);
  gemm_kernel<false><<<dim3(16, 8),  256, 0, stream>>>(hs_ln, Wqt, bq, Qm, 2048, 1024, QSC);
  gemm_kernel<false><<<dim3(128, 8), 256, 0, stream>>>(in_ln, Wkt, bk, Km, 16384, 768, 1.0f);
  gemm_kernel<true ><<<dim3(128, 8), 256, 0, stream>>>(in_ln, Wvt, bv, Vt, 16384, 768, 1.0f);
  attn_kernel<<<512, 512, 0, stream>>>(Qm, Km, Vt, ctxp, mlp);
  combine_kernel<<<NROWS / 4, 256, 0, stream>>>(ctxp, mlp, (float*)d_out);
}

// Round 6
// 253.826 us; speedup vs baseline: 1.8999x; 1.2741x over previous
//
#include <hip/hip_runtime.h>
#include <hip/hip_bf16.h>
#include <stdint.h>

#define B_    4
#define QL_   512
#define KVL_  4096
#define QDIM  1024
#define KVDIM 768
#define NCH   1024
#define H_    8
#define DH    128
#define NROWS (B_ * H_ * QL_)   // 16384 partial rows
#define KVBLK 64
#define NS    4

typedef unsigned short ushort_t;
typedef __attribute__((ext_vector_type(8))) short bf16x8;
typedef __attribute__((ext_vector_type(4))) float f32x4;
typedef __attribute__((ext_vector_type(4))) unsigned short us4;

__device__ __forceinline__ ushort_t f2bf(float x){
  union { float f; unsigned u; } v; v.f = x;
  unsigned r = v.u + 0x7FFF + ((v.u >> 16) & 1);
  return (ushort_t)(r >> 16);
}

__device__ __forceinline__ void gload16(void* l, const void* g){
  __builtin_amdgcn_global_load_lds(
    (const __attribute__((address_space(1))) unsigned int*)g,
    (__attribute__((address_space(3))) unsigned int*)l, 16, 0, 0);
}

// ---------------- LayerNorm + bf16 cast ----------------
template<int D>
__global__ void ln_kernel(const float* __restrict__ x, const float* __restrict__ gamma,
                          const float* __restrict__ beta, ushort_t* __restrict__ out){
  int row = blockIdx.x;
  const float* xr = x + (size_t)row * D;
  ushort_t* orow = out + (size_t)row * D;
  int tid = threadIdx.x;
  constexpr int NPT = D / 256;
  float v[NPT];
  float s = 0.f, s2 = 0.f;
  #pragma unroll
  for (int k = 0; k < NPT; ++k){ v[k] = xr[tid + k*256]; s += v[k]; s2 += v[k]*v[k]; }
  #pragma unroll
  for (int m = 32; m; m >>= 1){ s += __shfl_xor(s, m); s2 += __shfl_xor(s2, m); }
  __shared__ float red[8];
  int w = tid >> 6;
  if ((tid & 63) == 0){ red[w] = s; red[4 + w] = s2; }
  __syncthreads();
  s  = red[0] + red[1] + red[2] + red[3];
  s2 = red[4] + red[5] + red[6] + red[7];
  float mu  = s / D;
  float var = s2 / D - mu * mu;
  float rs  = rsqrtf(var + 1e-3f);
  #pragma unroll
  for (int k = 0; k < NPT; ++k){
    int i = tid + k*256;
    orow[i] = f2bf((v[k] - mu) * rs * gamma[i] + beta[i]);
  }
}

// ---------------- Weight transpose + bf16 cast: Wt[n][k] = W[k][n] ----------------
__global__ void wtrans_kernel(const float* __restrict__ W, ushort_t* __restrict__ Wt,
                              int K, int N){
  __shared__ float t[32][33];
  int n0 = blockIdx.x * 32, k0 = blockIdx.y * 32;
  int tx = threadIdx.x & 31, ty = threadIdx.x >> 5;   // 32 x 8
  #pragma unroll
  for (int i = 0; i < 32; i += 8) t[ty + i][tx] = W[(size_t)(k0 + ty + i) * N + n0 + tx];
  __syncthreads();
  #pragma unroll
  for (int i = 0; i < 32; i += 8)
    Wt[(size_t)(n0 + ty + i) * K + k0 + tx] = f2bf(t[tx][ty + i]);
}

// ---------------- GEMM: C[m][n] = (sum_k A[m][k]*Bw[n][k] + bias[n]) * oscale ----------------
// TRANSV: scatter into Vt[b][h][dv][c] with kv->c column permutation
// c = (kv&~31) | ((kv&15)>>2)<<3 | ((kv>>4)&1)<<2 | (kv&3)  (PV A-frag k-slot order)
template<bool TRANSV>
__global__ __launch_bounds__(256)
void gemm_kernel(const ushort_t* __restrict__ A, const ushort_t* __restrict__ Bw,
                 const float* __restrict__ bias, ushort_t* __restrict__ out,
                 int M, int K, float oscale){
  __shared__ __align__(16) ushort_t lds[2][4][128][8];
  int tid = threadIdx.x;
  int w = tid >> 6, lane = tid & 63;
  int m0 = blockIdx.x * 128, n0 = blockIdx.y * 128;
  int wr = w >> 1, wc = w & 1;
  int g = lane >> 4, j = lane & 15;
  f32x4 acc[4][4] = {};
  const int ksteps = K / 32;
  const ushort_t* Aw  = A  + (size_t)(m0 + lane) * K + w * 8;
  const ushort_t* Bww = Bw + (size_t)(n0 + lane) * K + w * 8;
  for (int ks = 0; ks < ksteps; ++ks){
    #pragma unroll
    for (int i = 0; i < 2; ++i){
      gload16(&lds[0][w][i*64][0], Aw  + (size_t)i*64*K + ks*32);
      gload16(&lds[1][w][i*64][0], Bww + (size_t)i*64*K + ks*32);
    }
    __syncthreads();
    bf16x8 af[4], bfr[4];
    #pragma unroll
    for (int mi = 0; mi < 4; ++mi) af[mi]  = *(const bf16x8*)&lds[0][g][wr*64 + mi*16 + j][0];
    #pragma unroll
    for (int ni = 0; ni < 4; ++ni) bfr[ni] = *(const bf16x8*)&lds[1][g][wc*64 + ni*16 + j][0];
    #pragma unroll
    for (int mi = 0; mi < 4; ++mi)
      #pragma unroll
      for (int ni = 0; ni < 4; ++ni)
        acc[mi][ni] = __builtin_amdgcn_mfma_f32_16x16x32_bf16(af[mi], bfr[ni], acc[mi][ni], 0, 0, 0);
    __syncthreads();
  }
  #pragma unroll
  for (int mi = 0; mi < 4; ++mi){
    int row0 = m0 + wr*64 + mi*16 + g*4;
    #pragma unroll
    for (int ni = 0; ni < 4; ++ni){
      int col = n0 + wc*64 + ni*16 + j;
      float bs = bias[col];
      if (!TRANSV){
        #pragma unroll
        for (int r = 0; r < 4; ++r)
          out[(size_t)(row0 + r) * NCH + col] = f2bf((acc[mi][ni][r] + bs) * oscale);
      } else {
        int bidx = row0 >> 12, kv = row0 & (KVL_ - 1);
        int h = col >> 7, dv = col & 127;
        int c = (kv & ~31) | (((kv & 15) >> 2) << 3) | (((kv >> 4) & 1) << 2);
        us4 pk;
        #pragma unroll
        for (int r = 0; r < 4; ++r) pk[r] = f2bf(acc[mi][ni][r] + bs);
        *(us4*)&out[((size_t)(bidx * H_ + h) * DH + dv) * KVL_ + c] = pk;
      }
    }
  }
}

// ---------------- Flash attention: swapped QK^T, in-register softmax ----------------
// Q pre-scaled by (1/sqrt(DH))*log2(e): scores in log2 domain.
// grid = 512. bid = xcd + 8*slot; p = xcd + 8*(slot>>2) -> (bh, sp); qb = slot&3.
// Lane (j,g): softmax owns q-row j (16 kv scores in regs); ctx rows are q = 4g+r.
__global__ __launch_bounds__(512, 4)
void attn_kernel(const ushort_t* __restrict__ Q, const ushort_t* __restrict__ Km,
                 const ushort_t* __restrict__ Vt, float* __restrict__ ctxp,
                 float* __restrict__ mlp){
  __shared__ __align__(16) ushort_t Kbuf[2][KVBLK][DH];   // 32 KB
  __shared__ __align__(16) ushort_t Vbuf[2][DH][KVBLK];   // 32 KB (columns pre-permuted)

  int bid = blockIdx.x;
  int xcd = bid & 7, slot = bid >> 3;
  int p   = xcd + 8 * (slot >> 2);       // 0..127 -> (bh, sp)
  int qb  = slot & 3;
  int bh  = p >> 2, sp = p & 3;
  int b = bh >> 3, h = bh & 7;

  int tid = threadIdx.x;
  int w = tid >> 6, lane = tid & 63;
  int g = lane >> 4, j = lane & 15;
  int qbase = qb * 128 + w * 16;          // wave's 16 q-rows

  bf16x8 qreg[4];                          // Q[qbase+j][kb*32 + g*8 + e]
  {
    const ushort_t* Qb = Q + (size_t)(b * QL_ + qbase + j) * NCH + h * DH + g * 8;
    #pragma unroll
    for (int kb = 0; kb < 4; ++kb) qreg[kb] = *(const bf16x8*)(Qb + kb * 32);
  }

  f32x4 ctx[8] = {};
  float m_ = -1e30f, l_ = 0.f;

  const int kvbeg = sp * (KVL_ / NS);
  const char* Kg = (const char*)(Km + (size_t)b * KVL_ * NCH) + h * 256;
  const char* Vg = (const char*)(Vt + (size_t)(b * H_ + h) * DH * KVL_);

  auto stage = [&](int bi, int kv0){
    #pragma unroll
    for (int i = 0; i < 2; ++i){
      int lin = (i * 512 + tid) * 16;
      int sw  = lin ^ (((lin >> 8) & 7) << 4);
      gload16((char*)&Kbuf[bi][0][0] + lin,
              Kg + (size_t)(kv0 + (sw >> 8)) * 2048 + (sw & 255));
    }
    #pragma unroll
    for (int i = 0; i < 2; ++i){
      int lin = (i * 512 + tid) * 16;
      int sw  = lin ^ (((lin >> 7) & 7) << 4);
      gload16((char*)&Vbuf[bi][0][0] + lin,
              Vg + (size_t)(sw >> 7) * (KVL_ * 2) + kv0 * 2 + (sw & 127));
    }
  };

  const float THR = 11.5415603f;            // 8 * log2(e)
  const int NCHUNK = (KVL_ / NS) / KVBLK;   // 16

  stage(0, kvbeg);
  __syncthreads();

  for (int c = 0; c < NCHUNK; ++c){
    int bi = c & 1;
    if (c + 1 < NCHUNK) stage(bi ^ 1, kvbeg + (c + 1) * KVBLK);

    const char* Kl = (const char*)&Kbuf[bi][0][0];
    const char* Vl = (const char*)&Vbuf[bi][0][0];

    // QK^T swapped: s[kf][r] = S[kv = kf*16 + 4g + r][q = j]
    f32x4 s[4] = {};
    __builtin_amdgcn_s_setprio(1);
    #pragma unroll
    for (int kf = 0; kf < 4; ++kf){
      #pragma unroll
      for (int kb = 0; kb < 4; ++kb){
        int off = (kf * 16 + j) * 256 + kb * 64 + g * 16;
        off ^= ((j & 7) << 4);
        s[kf] = __builtin_amdgcn_mfma_f32_16x16x32_bf16(
                  *(const bf16x8*)(Kl + off), qreg[kb], s[kf], 0, 0, 0);
      }
    }
    __builtin_amdgcn_s_setprio(0);

    // online softmax for q-row j: in-lane over 16 + cross-g (lanes ^16, ^32)
    float pm = s[0][0];
    #pragma unroll
    for (int kf = 0; kf < 4; ++kf)
      #pragma unroll
      for (int r = 0; r < 4; ++r) pm = fmaxf(pm, s[kf][r]);
    pm = fmaxf(pm, __shfl_xor(pm, 16));
    pm = fmaxf(pm, __shfl_xor(pm, 32));
    int ok = (pm - m_ <= THR);
    if (!__all(ok)){
      float mn = fmaxf(m_, pm);
      float cf = exp2f(m_ - mn);
      m_ = mn;
      l_ *= cf;
      float cfr[4];
      #pragma unroll
      for (int r = 0; r < 4; ++r) cfr[r] = __shfl(cf, g * 4 + r);
      #pragma unroll
      for (int df = 0; df < 8; ++df)
        #pragma unroll
        for (int r = 0; r < 4; ++r) ctx[df][r] *= cfr[r];
    }
    float rs = 0.f;
    #pragma unroll
    for (int kf = 0; kf < 4; ++kf)
      #pragma unroll
      for (int r = 0; r < 4; ++r){ s[kf][r] = exp2f(s[kf][r] - m_); rs += s[kf][r]; }
    rs += __shfl_xor(rs, 16);
    rs += __shfl_xor(rs, 32);
    l_ += rs;

    // P -> bf16 A-frags, fully in-register (V columns pre-permuted to match)
    union { unsigned u[4]; bf16x8 v; } pa[2];
    #pragma unroll
    for (int kb = 0; kb < 2; ++kb){
      asm("v_cvt_pk_bf16_f32 %0, %1, %2" : "=v"(pa[kb].u[0]) : "v"(s[2*kb][0]),   "v"(s[2*kb][1]));
      asm("v_cvt_pk_bf16_f32 %0, %1, %2" : "=v"(pa[kb].u[1]) : "v"(s[2*kb][2]),   "v"(s[2*kb][3]));
      asm("v_cvt_pk_bf16_f32 %0, %1, %2" : "=v"(pa[kb].u[2]) : "v"(s[2*kb+1][0]), "v"(s[2*kb+1][1]));
      asm("v_cvt_pk_bf16_f32 %0, %1, %2" : "=v"(pa[kb].u[3]) : "v"(s[2*kb+1][2]), "v"(s[2*kb+1][3]));
    }

    // PV: ctx[df][r] = O[q = 4g+r][dv = df*16 + j]
    __builtin_amdgcn_s_setprio(1);
    #pragma unroll
    for (int df = 0; df < 8; ++df){
      int off0 = (df * 16 + j) * 128 + g * 16;        int o0 = off0 ^ ((j & 7) << 4);
      int off1 = (df * 16 + j) * 128 + 64 + g * 16;   int o1 = off1 ^ ((j & 7) << 4);
      ctx[df] = __builtin_amdgcn_mfma_f32_16x16x32_bf16(pa[0].v, *(const bf16x8*)(Vl + o0), ctx[df], 0, 0, 0);
      ctx[df] = __builtin_amdgcn_mfma_f32_16x16x32_bf16(pa[1].v, *(const bf16x8*)(Vl + o1), ctx[df], 0, 0, 0);
    }
    __builtin_amdgcn_s_setprio(0);
    __syncthreads();
  }

  size_t prow0 = ((size_t)sp * 32 + bh) * QL_ + qbase;
  #pragma unroll
  for (int r = 0; r < 4; ++r){
    float* cp = ctxp + (prow0 + g * 4 + r) * DH;
    #pragma unroll
    for (int df = 0; df < 8; ++df) cp[df * 16 + j] = ctx[df][r];
  }
  if (g == 0){
    mlp[(prow0 + j) * 2]     = m_;
    mlp[(prow0 + j) * 2 + 1] = l_;
  }
}

// ---------------- Split combine: 1 wave per q-row (m in log2 domain) ----------------
__global__ __launch_bounds__(256)
void combine_kernel(const float* __restrict__ ctxp, const float* __restrict__ mlp,
                    float* __restrict__ out){
  int row = blockIdx.x * 4 + (threadIdx.x >> 6);   // (b*8+h)*512 + q
  int lane = threadIdx.x & 63;
  int b = row >> 12, h = (row >> 9) & 7, q = row & 511;
  float ms[NS], ls[NS];
  #pragma unroll
  for (int s = 0; s < NS; ++s){
    ms[s] = mlp[((size_t)(s * NROWS + row)) * 2];
    ls[s] = mlp[((size_t)(s * NROWS + row)) * 2 + 1];
  }
  float M = ms[0];
  #pragma unroll
  for (int s = 1; s < NS; ++s) M = fmaxf(M, ms[s]);
  float wgt[NS], L = 0.f;
  #pragma unroll
  for (int s = 0; s < NS; ++s){ wgt[s] = exp2f(ms[s] - M); L += ls[s] * wgt[s]; }
  float inv = 1.f / L;
  float ax = 0.f, ay = 0.f;
  #pragma unroll
  for (int s = 0; s < NS; ++s){
    const float* cp = ctxp + ((size_t)(s * NROWS + row)) * DH + lane * 2;
    ax += cp[0] * wgt[s]; ay += cp[1] * wgt[s];
  }
  float* op = out + ((size_t)(b * QL_ + q)) * NCH + h * DH + lane * 2;
  op[0] = ax * inv; op[1] = ay * inv;
}

extern "C" void kernel_launch(void* const* d_in, const int* in_sizes, int n_in,
                              void* d_out, int out_size, void* d_ws, size_t ws_size,
                              hipStream_t stream){
  const float* hs   = (const float*)d_in[0];
  const float* inp  = (const float*)d_in[1];
  const float* ln1g = (const float*)d_in[2];
  const float* ln1b = (const float*)d_in[3];
  const float* ln2g = (const float*)d_in[4];
  const float* ln2b = (const float*)d_in[5];
  const float* Wq   = (const float*)d_in[6];
  const float* bq   = (const float*)d_in[7];
  const float* Wk   = (const float*)d_in[8];
  const float* bk   = (const float*)d_in[9];
  const float* Wv   = (const float*)d_in[10];
  const float* bv   = (const float*)d_in[11];

  char* ws = (char*)d_ws;
  size_t off = 0;
  auto alloc = [&](size_t bytes){ void* pp = ws + off; off += (bytes + 255) & ~255ull; return pp; };
  // persistent across phases
  ushort_t* Qm = (ushort_t*)alloc((size_t)2048 * 1024 * 2);
  ushort_t* Km = (ushort_t*)alloc((size_t)16384 * 1024 * 2);
  ushort_t* Vt = (ushort_t*)alloc((size_t)16384 * 1024 * 2);
  size_t base2 = off;
  // phase 1: LN outputs + transposed weights (dead after the GEMMs)
  ushort_t* hs_ln = (ushort_t*)alloc((size_t)2048 * 1024 * 2);
  ushort_t* in_ln = (ushort_t*)alloc((size_t)16384 * 768 * 2);
  ushort_t* Wqt   = (ushort_t*)alloc((size_t)1024 * 1024 * 2);
  ushort_t* Wkt   = (ushort_t*)alloc((size_t)1024 * 768 * 2);
  ushort_t* Wvt   = (ushort_t*)alloc((size_t)1024 * 768 * 2);
  // phase 2: attention partials (alias phase 1)
  off = base2;
  float* ctxp = (float*)alloc((size_t)NS * NROWS * DH * 4);
  float* mlp  = (float*)alloc((size_t)NS * NROWS * 2 * 4);

  const float QSC = 0.08838834764831845f * 1.4426950408889634f;  // 1/sqrt(128)*log2(e)

  ln_kernel<1024><<<2048, 256, 0, stream>>>(hs, ln1g, ln1b, hs_ln);
  ln_kernel<768><<<16384, 256, 0, stream>>>(inp, ln2g, ln2b, in_ln);
  wtrans_kernel<<<dim3(32, 32), 256, 0, stream>>>(Wq, Wqt, 1024, 1024);
  wtrans_kernel<<<dim3(32, 24), 256, 0, stream>>>(Wk, Wkt, 768, 1024);
  wtrans_kernel<<<dim3(32, 24), 256, 0, stream>>>(Wv, Wvt, 768, 1024);
  gemm_kernel<false><<<dim3(16, 8),  256, 0, stream>>>(hs_ln, Wqt, bq, Qm, 2048, 1024, QSC);
  gemm_kernel<false><<<dim3(128, 8), 256, 0, stream>>>(in_ln, Wkt, bk, Km, 16384, 768, 1.0f);
  gemm_kernel<true ><<<dim3(128, 8), 256, 0, stream>>>(in_ln, Wvt, bv, Vt, 16384, 768, 1.0f);
  attn_kernel<<<512, 512, 0, stream>>>(Qm, Km, Vt, ctxp, mlp);
  combine_kernel<<<NROWS / 4, 256, 0, stream>>>(ctxp, mlp, (float*)d_out);
}

// Round 7
// 234.654 us; speedup vs baseline: 2.0551x; 1.0817x over previous
//
#include <hip/hip_runtime.h>
#include <hip/hip_bf16.h>
#include <stdint.h>

#define B_    4
#define QL_   512
#define KVL_  4096
#define QDIM  1024
#define KVDIM 768
#define NCH   1024
#define H_    8
#define DH    128
#define NROWS (B_ * H_ * QL_)   // 16384 partial rows
#define KVBLK 64
#define NS    4

typedef unsigned short ushort_t;
typedef __attribute__((ext_vector_type(8))) short bf16x8;
typedef __attribute__((ext_vector_type(4))) float f32x4;
typedef __attribute__((ext_vector_type(4))) unsigned short us4;

__device__ __forceinline__ ushort_t f2bf(float x){
  union { float f; unsigned u; } v; v.f = x;
  unsigned r = v.u + 0x7FFF + ((v.u >> 16) & 1);
  return (ushort_t)(r >> 16);
}

__device__ __forceinline__ void gload16(void* l, const void* g){
  __builtin_amdgcn_global_load_lds(
    (const __attribute__((address_space(1))) unsigned int*)g,
    (__attribute__((address_space(3))) unsigned int*)l, 16, 0, 0);
}

// ---------------- LayerNorm + bf16 cast ----------------
template<int D>
__global__ void ln_kernel(const float* __restrict__ x, const float* __restrict__ gamma,
                          const float* __restrict__ beta, ushort_t* __restrict__ out){
  int row = blockIdx.x;
  const float* xr = x + (size_t)row * D;
  ushort_t* orow = out + (size_t)row * D;
  int tid = threadIdx.x;
  constexpr int NPT = D / 256;
  float v[NPT];
  float s = 0.f, s2 = 0.f;
  #pragma unroll
  for (int k = 0; k < NPT; ++k){ v[k] = xr[tid + k*256]; s += v[k]; s2 += v[k]*v[k]; }
  #pragma unroll
  for (int m = 32; m; m >>= 1){ s += __shfl_xor(s, m); s2 += __shfl_xor(s2, m); }
  __shared__ float red[8];
  int w = tid >> 6;
  if ((tid & 63) == 0){ red[w] = s; red[4 + w] = s2; }
  __syncthreads();
  s  = red[0] + red[1] + red[2] + red[3];
  s2 = red[4] + red[5] + red[6] + red[7];
  float mu  = s / D;
  float var = s2 / D - mu * mu;
  float rs  = rsqrtf(var + 1e-3f);
  #pragma unroll
  for (int k = 0; k < NPT; ++k){
    int i = tid + k*256;
    orow[i] = f2bf((v[k] - mu) * rs * gamma[i] + beta[i]);
  }
}

// ---------------- Weight transpose + bf16 cast: Wt[n][k] = W[k][n] ----------------
__global__ void wtrans_kernel(const float* __restrict__ W, ushort_t* __restrict__ Wt,
                              int K, int N){
  __shared__ float t[32][33];
  int n0 = blockIdx.x * 32, k0 = blockIdx.y * 32;
  int tx = threadIdx.x & 31, ty = threadIdx.x >> 5;   // 32 x 8
  #pragma unroll
  for (int i = 0; i < 32; i += 8) t[ty + i][tx] = W[(size_t)(k0 + ty + i) * N + n0 + tx];
  __syncthreads();
  #pragma unroll
  for (int i = 0; i < 32; i += 8)
    Wt[(size_t)(n0 + ty + i) * K + k0 + tx] = f2bf(t[tx][ty + i]);
}

// ---------------- GEMM: C[m][n] = (sum_k A[m][k]*Bw[n][k] + bias[n]) * oscale ----------------
// 2-phase double-buffered staging: stage(ks+1) issued before compute(ks); 1 barrier/K-step.
// TRANSV: scatter into Vt[b][h][dv][c] with kv->c column permutation
// c = (kv&~31) | ((kv&15)>>2)<<3 | ((kv>>4)&1)<<2 | (kv&3)  (PV A-frag k-slot order)
template<bool TRANSV>
__global__ __launch_bounds__(256)
void gemm_kernel(const ushort_t* __restrict__ A, const ushort_t* __restrict__ Bw,
                 const float* __restrict__ bias, ushort_t* __restrict__ out,
                 int M, int K, float oscale){
  __shared__ __align__(16) ushort_t lds[2][2][4][128][8];   // [buf][op][g][row][8] = 32 KB
  int tid = threadIdx.x;
  int w = tid >> 6, lane = tid & 63;
  int m0 = blockIdx.x * 128, n0 = blockIdx.y * 128;
  int wr = w >> 1, wc = w & 1;
  int g = lane >> 4, j = lane & 15;
  f32x4 acc[4][4] = {};
  const int ksteps = K / 32;
  const ushort_t* Aw  = A  + (size_t)(m0 + lane) * K + w * 8;
  const ushort_t* Bww = Bw + (size_t)(n0 + lane) * K + w * 8;

  auto stage = [&](int buf, int ks){
    #pragma unroll
    for (int i = 0; i < 2; ++i){
      gload16(&lds[buf][0][w][i*64][0], Aw  + (size_t)i*64*K + ks*32);
      gload16(&lds[buf][1][w][i*64][0], Bww + (size_t)i*64*K + ks*32);
    }
  };

  stage(0, 0);
  __syncthreads();
  int cur = 0;
  for (int ks = 0; ks < ksteps; ++ks){
    if (ks + 1 < ksteps) stage(cur ^ 1, ks + 1);   // loads fly during compute below
    bf16x8 af[4], bfr[4];
    #pragma unroll
    for (int mi = 0; mi < 4; ++mi) af[mi]  = *(const bf16x8*)&lds[cur][0][g][wr*64 + mi*16 + j][0];
    #pragma unroll
    for (int ni = 0; ni < 4; ++ni) bfr[ni] = *(const bf16x8*)&lds[cur][1][g][wc*64 + ni*16 + j][0];
    __builtin_amdgcn_s_setprio(1);
    #pragma unroll
    for (int mi = 0; mi < 4; ++mi)
      #pragma unroll
      for (int ni = 0; ni < 4; ++ni)
        acc[mi][ni] = __builtin_amdgcn_mfma_f32_16x16x32_bf16(af[mi], bfr[ni], acc[mi][ni], 0, 0, 0);
    __builtin_amdgcn_s_setprio(0);
    __syncthreads();          // publishes tile ks+1, protects buf[cur] for ks+2
    cur ^= 1;
  }

  #pragma unroll
  for (int mi = 0; mi < 4; ++mi){
    int row0 = m0 + wr*64 + mi*16 + g*4;
    #pragma unroll
    for (int ni = 0; ni < 4; ++ni){
      int col = n0 + wc*64 + ni*16 + j;
      float bs = bias[col];
      if (!TRANSV){
        #pragma unroll
        for (int r = 0; r < 4; ++r)
          out[(size_t)(row0 + r) * NCH + col] = f2bf((acc[mi][ni][r] + bs) * oscale);
      } else {
        int bidx = row0 >> 12, kv = row0 & (KVL_ - 1);
        int h = col >> 7, dv = col & 127;
        int c = (kv & ~31) | (((kv & 15) >> 2) << 3) | (((kv >> 4) & 1) << 2);
        us4 pk;
        #pragma unroll
        for (int r = 0; r < 4; ++r) pk[r] = f2bf(acc[mi][ni][r] + bs);
        *(us4*)&out[((size_t)(bidx * H_ + h) * DH + dv) * KVL_ + c] = pk;
      }
    }
  }
}

// ---------------- Flash attention: swapped QK^T, in-register softmax ----------------
// Q pre-scaled by (1/sqrt(DH))*log2(e): scores in log2 domain.
// grid = 512. bid = xcd + 8*slot; p = xcd + 8*(slot>>2) -> (bh, sp); qb = slot&3.
// Lane (j,g): softmax owns q-row j (16 kv scores in regs); ctx rows are q = 4g+r.
__global__ __launch_bounds__(512, 4)
void attn_kernel(const ushort_t* __restrict__ Q, const ushort_t* __restrict__ Km,
                 const ushort_t* __restrict__ Vt, float* __restrict__ ctxp,
                 float* __restrict__ mlp){
  __shared__ __align__(16) ushort_t Kbuf[2][KVBLK][DH];   // 32 KB
  __shared__ __align__(16) ushort_t Vbuf[2][DH][KVBLK];   // 32 KB (columns pre-permuted)

  int bid = blockIdx.x;
  int xcd = bid & 7, slot = bid >> 3;
  int p   = xcd + 8 * (slot >> 2);       // 0..127 -> (bh, sp)
  int qb  = slot & 3;
  int bh  = p >> 2, sp = p & 3;
  int b = bh >> 3, h = bh & 7;

  int tid = threadIdx.x;
  int w = tid >> 6, lane = tid & 63;
  int g = lane >> 4, j = lane & 15;
  int qbase = qb * 128 + w * 16;          // wave's 16 q-rows

  bf16x8 qreg[4];                          // Q[qbase+j][kb*32 + g*8 + e]
  {
    const ushort_t* Qb = Q + (size_t)(b * QL_ + qbase + j) * NCH + h * DH + g * 8;
    #pragma unroll
    for (int kb = 0; kb < 4; ++kb) qreg[kb] = *(const bf16x8*)(Qb + kb * 32);
  }

  f32x4 ctx[8] = {};
  float m_ = -1e30f, l_ = 0.f;

  const int kvbeg = sp * (KVL_ / NS);
  const char* Kg = (const char*)(Km + (size_t)b * KVL_ * NCH) + h * 256;
  const char* Vg = (const char*)(Vt + (size_t)(b * H_ + h) * DH * KVL_);

  auto stage = [&](int bi, int kv0){
    #pragma unroll
    for (int i = 0; i < 2; ++i){
      int lin = (i * 512 + tid) * 16;
      int sw  = lin ^ (((lin >> 8) & 7) << 4);
      gload16((char*)&Kbuf[bi][0][0] + lin,
              Kg + (size_t)(kv0 + (sw >> 8)) * 2048 + (sw & 255));
    }
    #pragma unroll
    for (int i = 0; i < 2; ++i){
      int lin = (i * 512 + tid) * 16;
      int sw  = lin ^ (((lin >> 7) & 7) << 4);
      gload16((char*)&Vbuf[bi][0][0] + lin,
              Vg + (size_t)(sw >> 7) * (KVL_ * 2) + kv0 * 2 + (sw & 127));
    }
  };

  const float THR = 11.5415603f;            // 8 * log2(e)
  const int NCHUNK = (KVL_ / NS) / KVBLK;   // 16

  stage(0, kvbeg);
  __syncthreads();

  for (int c = 0; c < NCHUNK; ++c){
    int bi = c & 1;
    if (c + 1 < NCHUNK) stage(bi ^ 1, kvbeg + (c + 1) * KVBLK);

    const char* Kl = (const char*)&Kbuf[bi][0][0];
    const char* Vl = (const char*)&Vbuf[bi][0][0];

    // QK^T swapped: s[kf][r] = S[kv = kf*16 + 4g + r][q = j]
    f32x4 s[4] = {};
    __builtin_amdgcn_s_setprio(1);
    #pragma unroll
    for (int kf = 0; kf < 4; ++kf){
      #pragma unroll
      for (int kb = 0; kb < 4; ++kb){
        int off = (kf * 16 + j) * 256 + kb * 64 + g * 16;
        off ^= ((j & 7) << 4);
        s[kf] = __builtin_amdgcn_mfma_f32_16x16x32_bf16(
                  *(const bf16x8*)(Kl + off), qreg[kb], s[kf], 0, 0, 0);
      }
    }
    __builtin_amdgcn_s_setprio(0);

    // online softmax for q-row j: in-lane over 16 + cross-g (lanes ^16, ^32)
    float pm = s[0][0];
    #pragma unroll
    for (int kf = 0; kf < 4; ++kf)
      #pragma unroll
      for (int r = 0; r < 4; ++r) pm = fmaxf(pm, s[kf][r]);
    pm = fmaxf(pm, __shfl_xor(pm, 16));
    pm = fmaxf(pm, __shfl_xor(pm, 32));
    int ok = (pm - m_ <= THR);
    if (!__all(ok)){
      float mn = fmaxf(m_, pm);
      float cf = exp2f(m_ - mn);
      m_ = mn;
      l_ *= cf;
      float cfr[4];
      #pragma unroll
      for (int r = 0; r < 4; ++r) cfr[r] = __shfl(cf, g * 4 + r);
      #pragma unroll
      for (int df = 0; df < 8; ++df)
        #pragma unroll
        for (int r = 0; r < 4; ++r) ctx[df][r] *= cfr[r];
    }
    float rs = 0.f;
    #pragma unroll
    for (int kf = 0; kf < 4; ++kf)
      #pragma unroll
      for (int r = 0; r < 4; ++r){ s[kf][r] = exp2f(s[kf][r] - m_); rs += s[kf][r]; }
    rs += __shfl_xor(rs, 16);
    rs += __shfl_xor(rs, 32);
    l_ += rs;

    // P -> bf16 A-frags, fully in-register (V columns pre-permuted to match)
    union { unsigned u[4]; bf16x8 v; } pa[2];
    #pragma unroll
    for (int kb = 0; kb < 2; ++kb){
      asm("v_cvt_pk_bf16_f32 %0, %1, %2" : "=v"(pa[kb].u[0]) : "v"(s[2*kb][0]),   "v"(s[2*kb][1]));
      asm("v_cvt_pk_bf16_f32 %0, %1, %2" : "=v"(pa[kb].u[1]) : "v"(s[2*kb][2]),   "v"(s[2*kb][3]));
      asm("v_cvt_pk_bf16_f32 %0, %1, %2" : "=v"(pa[kb].u[2]) : "v"(s[2*kb+1][0]), "v"(s[2*kb+1][1]));
      asm("v_cvt_pk_bf16_f32 %0, %1, %2" : "=v"(pa[kb].u[3]) : "v"(s[2*kb+1][2]), "v"(s[2*kb+1][3]));
    }

    // PV: ctx[df][r] = O[q = 4g+r][dv = df*16 + j]
    __builtin_amdgcn_s_setprio(1);
    #pragma unroll
    for (int df = 0; df < 8; ++df){
      int off0 = (df * 16 + j) * 128 + g * 16;        int o0 = off0 ^ ((j & 7) << 4);
      int off1 = (df * 16 + j) * 128 + 64 + g * 16;   int o1 = off1 ^ ((j & 7) << 4);
      ctx[df] = __builtin_amdgcn_mfma_f32_16x16x32_bf16(pa[0].v, *(const bf16x8*)(Vl + o0), ctx[df], 0, 0, 0);
      ctx[df] = __builtin_amdgcn_mfma_f32_16x16x32_bf16(pa[1].v, *(const bf16x8*)(Vl + o1), ctx[df], 0, 0, 0);
    }
    __builtin_amdgcn_s_setprio(0);
    __syncthreads();
  }

  size_t prow0 = ((size_t)sp * 32 + bh) * QL_ + qbase;
  #pragma unroll
  for (int r = 0; r < 4; ++r){
    float* cp = ctxp + (prow0 + g * 4 + r) * DH;
    #pragma unroll
    for (int df = 0; df < 8; ++df) cp[df * 16 + j] = ctx[df][r];
  }
  if (g == 0){
    mlp[(prow0 + j) * 2]     = m_;
    mlp[(prow0 + j) * 2 + 1] = l_;
  }
}

// ---------------- Split combine: 1 wave per q-row (m in log2 domain) ----------------
__global__ __launch_bounds__(256)
void combine_kernel(const float* __restrict__ ctxp, const float* __restrict__ mlp,
                    float* __restrict__ out){
  int row = blockIdx.x * 4 + (threadIdx.x >> 6);   // (b*8+h)*512 + q
  int lane = threadIdx.x & 63;
  int b = row >> 12, h = (row >> 9) & 7, q = row & 511;
  float ms[NS], ls[NS];
  #pragma unroll
  for (int s = 0; s < NS; ++s){
    ms[s] = mlp[((size_t)(s * NROWS + row)) * 2];
    ls[s] = mlp[((size_t)(s * NROWS + row)) * 2 + 1];
  }
  float M = ms[0];
  #pragma unroll
  for (int s = 1; s < NS; ++s) M = fmaxf(M, ms[s]);
  float wgt[NS], L = 0.f;
  #pragma unroll
  for (int s = 0; s < NS; ++s){ wgt[s] = exp2f(ms[s] - M); L += ls[s] * wgt[s]; }
  float inv = 1.f / L;
  float ax = 0.f, ay = 0.f;
  #pragma unroll
  for (int s = 0; s < NS; ++s){
    const float* cp = ctxp + ((size_t)(s * NROWS + row)) * DH + lane * 2;
    ax += cp[0] * wgt[s]; ay += cp[1] * wgt[s];
  }
  float* op = out + ((size_t)(b * QL_ + q)) * NCH + h * DH + lane * 2;
  op[0] = ax * inv; op[1] = ay * inv;
}

extern "C" void kernel_launch(void* const* d_in, const int* in_sizes, int n_in,
                              void* d_out, int out_size, void* d_ws, size_t ws_size,
                              hipStream_t stream){
  const float* hs   = (const float*)d_in[0];
  const float* inp  = (const float*)d_in[1];
  const float* ln1g = (const float*)d_in[2];
  const float* ln1b = (const float*)d_in[3];
  const float* ln2g = (const float*)d_in[4];
  const float* ln2b = (const float*)d_in[5];
  const float* Wq   = (const float*)d_in[6];
  const float* bq   = (const float*)d_in[7];
  const float* Wk   = (const float*)d_in[8];
  const float* bk   = (const float*)d_in[9];
  const float* Wv   = (const float*)d_in[10];
  const float* bv   = (const float*)d_in[11];

  char* ws = (char*)d_ws;
  size_t off = 0;
  auto alloc = [&](size_t bytes){ void* pp = ws + off; off += (bytes + 255) & ~255ull; return pp; };
  // persistent across phases
  ushort_t* Qm = (ushort_t*)alloc((size_t)2048 * 1024 * 2);
  ushort_t* Km = (ushort_t*)alloc((size_t)16384 * 1024 * 2);
  ushort_t* Vt = (ushort_t*)alloc((size_t)16384 * 1024 * 2);
  size_t base2 = off;
  // phase 1: LN outputs + transposed weights (dead after the GEMMs)
  ushort_t* hs_ln = (ushort_t*)alloc((size_t)2048 * 1024 * 2);
  ushort_t* in_ln = (ushort_t*)alloc((size_t)16384 * 768 * 2);
  ushort_t* Wqt   = (ushort_t*)alloc((size_t)1024 * 1024 * 2);
  ushort_t* Wkt   = (ushort_t*)alloc((size_t)1024 * 768 * 2);
  ushort_t* Wvt   = (ushort_t*)alloc((size_t)1024 * 768 * 2);
  // phase 2: attention partials (alias phase 1)
  off = base2;
  float* ctxp = (float*)alloc((size_t)NS * NROWS * DH * 4);
  float* mlp  = (float*)alloc((size_t)NS * NROWS * 2 * 4);

  const float QSC = 0.08838834764831845f * 1.4426950408889634f;  // 1/sqrt(128)*log2(e)

  ln_kernel<1024><<<2048, 256, 0, stream>>>(hs, ln1g, ln1b, hs_ln);
  ln_kernel<768><<<16384, 256, 0, stream>>>(inp, ln2g, ln2b, in_ln);
  wtrans_kernel<<<dim3(32, 32), 256, 0, stream>>>(Wq, Wqt, 1024, 1024);
  wtrans_kernel<<<dim3(32, 24), 256, 0, stream>>>(Wk, Wkt, 768, 1024);
  wtrans_kernel<<<dim3(32, 24), 256, 0, stream>>>(Wv, Wvt, 768, 1024);
  gemm_kernel<false><<<dim3(16, 8),  256, 0, stream>>>(hs_ln, Wqt, bq, Qm, 2048, 1024, QSC);
  gemm_kernel<false><<<dim3(128, 8), 256, 0, stream>>>(in_ln, Wkt, bk, Km, 16384, 768, 1.0f);
  gemm_kernel<true ><<<dim3(128, 8), 256, 0, stream>>>(in_ln, Wvt, bv, Vt, 16384, 768, 1.0f);
  attn_kernel<<<512, 512, 0, stream>>>(Qm, Km, Vt, ctxp, mlp);
  combine_kernel<<<NROWS / 4, 256, 0, stream>>>(ctxp, mlp, (float*)d_out);
}

// Round 8
// 218.925 us; speedup vs baseline: 2.2027x; 1.0718x over previous
//
#include <hip/hip_runtime.h>
#include <hip/hip_bf16.h>
#include <stdint.h>

#define B_    4
#define QL_   512
#define KVL_  4096
#define QDIM  1024
#define KVDIM 768
#define NCH   1024
#define H_    8
#define DH    128
#define NROWS (B_ * H_ * QL_)   // 16384 partial rows
#define KVBLK 64
#define NS    4

typedef unsigned short ushort_t;
typedef __attribute__((ext_vector_type(8))) short bf16x8;
typedef __attribute__((ext_vector_type(4))) float f32x4;
typedef __attribute__((ext_vector_type(4))) unsigned short us4;

__device__ __forceinline__ ushort_t f2bf(float x){
  union { float f; unsigned u; } v; v.f = x;
  unsigned r = v.u + 0x7FFF + ((v.u >> 16) & 1);
  return (ushort_t)(r >> 16);
}

__device__ __forceinline__ void gload16(void* l, const void* g){
  __builtin_amdgcn_global_load_lds(
    (const __attribute__((address_space(1))) unsigned int*)g,
    (__attribute__((address_space(3))) unsigned int*)l, 16, 0, 0);
}

// ---------------- LayerNorm + bf16 cast ----------------
template<int D>
__global__ void ln_kernel(const float* __restrict__ x, const float* __restrict__ gamma,
                          const float* __restrict__ beta, ushort_t* __restrict__ out){
  int row = blockIdx.x;
  const float* xr = x + (size_t)row * D;
  ushort_t* orow = out + (size_t)row * D;
  int tid = threadIdx.x;
  constexpr int NPT = D / 256;
  float v[NPT];
  float s = 0.f, s2 = 0.f;
  #pragma unroll
  for (int k = 0; k < NPT; ++k){ v[k] = xr[tid + k*256]; s += v[k]; s2 += v[k]*v[k]; }
  #pragma unroll
  for (int m = 32; m; m >>= 1){ s += __shfl_xor(s, m); s2 += __shfl_xor(s2, m); }
  __shared__ float red[8];
  int w = tid >> 6;
  if ((tid & 63) == 0){ red[w] = s; red[4 + w] = s2; }
  __syncthreads();
  s  = red[0] + red[1] + red[2] + red[3];
  s2 = red[4] + red[5] + red[6] + red[7];
  float mu  = s / D;
  float var = s2 / D - mu * mu;
  float rs  = rsqrtf(var + 1e-3f);
  #pragma unroll
  for (int k = 0; k < NPT; ++k){
    int i = tid + k*256;
    orow[i] = f2bf((v[k] - mu) * rs * gamma[i] + beta[i]);
  }
}

// ---------------- Weight transpose + bf16 cast: Wt[n][k] = W[k][n] ----------------
__global__ void wtrans_kernel(const float* __restrict__ W, ushort_t* __restrict__ Wt,
                              int K, int N){
  __shared__ float t[32][33];
  int n0 = blockIdx.x * 32, k0 = blockIdx.y * 32;
  int tx = threadIdx.x & 31, ty = threadIdx.x >> 5;   // 32 x 8
  #pragma unroll
  for (int i = 0; i < 32; i += 8) t[ty + i][tx] = W[(size_t)(k0 + ty + i) * N + n0 + tx];
  __syncthreads();
  #pragma unroll
  for (int i = 0; i < 32; i += 8)
    Wt[(size_t)(n0 + ty + i) * K + k0 + tx] = f2bf(t[tx][ty + i]);
}

// ---------------- GEMM: C[m][n] = (sum_k A[m][k]*Bw[n][k] + bias[n]) * oscale ----------------
// 3-buffer pipeline, prefetch distance 2, counted vmcnt(4) + raw s_barrier (no vmcnt(0) drain).
// Race-free: stage(ks+2) targets buf[(ks+2)%3], last read in iter ks-1, separated by a barrier.
// TRANSV: scatter into Vt[b][h][dv][c] with kv->c column permutation
// c = (kv&~31) | ((kv&15)>>2)<<3 | ((kv>>4)&1)<<2 | (kv&3)  (PV A-frag k-slot order)
template<bool TRANSV>
__global__ __launch_bounds__(256)
void gemm_kernel(const ushort_t* __restrict__ A, const ushort_t* __restrict__ Bw,
                 const float* __restrict__ bias, ushort_t* __restrict__ out,
                 int M, int K, float oscale){
  __shared__ __align__(16) ushort_t lds[3][2][4][128][8];   // 48 KB, buf = ks%3
  int tid = threadIdx.x;
  int w = tid >> 6, lane = tid & 63;
  int m0 = blockIdx.x * 128, n0 = blockIdx.y * 128;
  int wr = w >> 1, wc = w & 1;
  int g = lane >> 4, j = lane & 15;
  f32x4 acc[4][4] = {};
  const int ksteps = K / 32;
  const ushort_t* Aw  = A  + (size_t)(m0 + lane) * K + w * 8;
  const ushort_t* Bww = Bw + (size_t)(n0 + lane) * K + w * 8;

  auto stage = [&](int buf, int ks){      // 4 loads/wave
    #pragma unroll
    for (int i = 0; i < 2; ++i){
      gload16(&lds[buf][0][w][i*64][0], Aw  + (size_t)i*64*K + ks*32);
      gload16(&lds[buf][1][w][i*64][0], Bww + (size_t)i*64*K + ks*32);
    }
  };

  stage(0, 0);
  stage(1, 1);
  asm volatile("s_waitcnt vmcnt(4)" ::: "memory");   // tile 0 landed, tile 1 in flight
  __builtin_amdgcn_s_barrier();
  __builtin_amdgcn_sched_barrier(0);

  int cur = 0;
  for (int ks = 0; ks < ksteps; ++ks){
    int nxt = cur + 2; if (nxt >= 3) nxt -= 3;
    bool pf = (ks + 2 < ksteps);
    if (pf) stage(nxt, ks + 2);           // lands some time over the next ~2 K-steps
    bf16x8 af[4], bfr[4];
    #pragma unroll
    for (int mi = 0; mi < 4; ++mi) af[mi]  = *(const bf16x8*)&lds[cur][0][g][wr*64 + mi*16 + j][0];
    #pragma unroll
    for (int ni = 0; ni < 4; ++ni) bfr[ni] = *(const bf16x8*)&lds[cur][1][g][wc*64 + ni*16 + j][0];
    __builtin_amdgcn_s_setprio(1);
    #pragma unroll
    for (int mi = 0; mi < 4; ++mi)
      #pragma unroll
      for (int ni = 0; ni < 4; ++ni)
        acc[mi][ni] = __builtin_amdgcn_mfma_f32_16x16x32_bf16(af[mi], bfr[ni], acc[mi][ni], 0, 0, 0);
    __builtin_amdgcn_s_setprio(0);
    if (pf) asm volatile("s_waitcnt vmcnt(4)" ::: "memory");  // ks+1 landed; ks+2 stays in flight
    else    asm volatile("s_waitcnt vmcnt(0)" ::: "memory");  // tail: everything landed
    __builtin_amdgcn_s_barrier();
    __builtin_amdgcn_sched_barrier(0);
    cur += 1; if (cur >= 3) cur -= 3;
  }

  #pragma unroll
  for (int mi = 0; mi < 4; ++mi){
    int row0 = m0 + wr*64 + mi*16 + g*4;
    #pragma unroll
    for (int ni = 0; ni < 4; ++ni){
      int col = n0 + wc*64 + ni*16 + j;
      float bs = bias[col];
      if (!TRANSV){
        #pragma unroll
        for (int r = 0; r < 4; ++r)
          out[(size_t)(row0 + r) * NCH + col] = f2bf((acc[mi][ni][r] + bs) * oscale);
      } else {
        int bidx = row0 >> 12, kv = row0 & (KVL_ - 1);
        int h = col >> 7, dv = col & 127;
        int c = (kv & ~31) | (((kv & 15) >> 2) << 3) | (((kv >> 4) & 1) << 2);
        us4 pk;
        #pragma unroll
        for (int r = 0; r < 4; ++r) pk[r] = f2bf(acc[mi][ni][r] + bs);
        *(us4*)&out[((size_t)(bidx * H_ + h) * DH + dv) * KVL_ + c] = pk;
      }
    }
  }
}

// ---------------- Flash attention: swapped QK^T, in-register softmax ----------------
// Q pre-scaled by (1/sqrt(DH))*log2(e): scores in log2 domain.
// grid = 512. bid = xcd + 8*slot; p = xcd + 8*(slot>>2) -> (bh, sp); qb = slot&3.
// Lane (j,g): softmax owns q-row j (16 kv scores in regs); ctx rows are q = 4g+r.
__global__ __launch_bounds__(512, 4)
void attn_kernel(const ushort_t* __restrict__ Q, const ushort_t* __restrict__ Km,
                 const ushort_t* __restrict__ Vt, float* __restrict__ ctxp,
                 float* __restrict__ mlp){
  __shared__ __align__(16) ushort_t Kbuf[2][KVBLK][DH];   // 32 KB
  __shared__ __align__(16) ushort_t Vbuf[2][DH][KVBLK];   // 32 KB (columns pre-permuted)

  int bid = blockIdx.x;
  int xcd = bid & 7, slot = bid >> 3;
  int p   = xcd + 8 * (slot >> 2);       // 0..127 -> (bh, sp)
  int qb  = slot & 3;
  int bh  = p >> 2, sp = p & 3;
  int b = bh >> 3, h = bh & 7;

  int tid = threadIdx.x;
  int w = tid >> 6, lane = tid & 63;
  int g = lane >> 4, j = lane & 15;
  int qbase = qb * 128 + w * 16;          // wave's 16 q-rows

  bf16x8 qreg[4];                          // Q[qbase+j][kb*32 + g*8 + e]
  {
    const ushort_t* Qb = Q + (size_t)(b * QL_ + qbase + j) * NCH + h * DH + g * 8;
    #pragma unroll
    for (int kb = 0; kb < 4; ++kb) qreg[kb] = *(const bf16x8*)(Qb + kb * 32);
  }

  f32x4 ctx[8] = {};
  float m_ = -1e30f, l_ = 0.f;

  const int kvbeg = sp * (KVL_ / NS);
  const char* Kg = (const char*)(Km + (size_t)b * KVL_ * NCH) + h * 256;
  const char* Vg = (const char*)(Vt + (size_t)(b * H_ + h) * DH * KVL_);

  auto stage = [&](int bi, int kv0){
    #pragma unroll
    for (int i = 0; i < 2; ++i){
      int lin = (i * 512 + tid) * 16;
      int sw  = lin ^ (((lin >> 8) & 7) << 4);
      gload16((char*)&Kbuf[bi][0][0] + lin,
              Kg + (size_t)(kv0 + (sw >> 8)) * 2048 + (sw & 255));
    }
    #pragma unroll
    for (int i = 0; i < 2; ++i){
      int lin = (i * 512 + tid) * 16;
      int sw  = lin ^ (((lin >> 7) & 7) << 4);
      gload16((char*)&Vbuf[bi][0][0] + lin,
              Vg + (size_t)(sw >> 7) * (KVL_ * 2) + kv0 * 2 + (sw & 127));
    }
  };

  const float THR = 11.5415603f;            // 8 * log2(e)
  const int NCHUNK = (KVL_ / NS) / KVBLK;   // 16

  stage(0, kvbeg);
  __syncthreads();

  for (int c = 0; c < NCHUNK; ++c){
    int bi = c & 1;
    if (c + 1 < NCHUNK) stage(bi ^ 1, kvbeg + (c + 1) * KVBLK);

    const char* Kl = (const char*)&Kbuf[bi][0][0];
    const char* Vl = (const char*)&Vbuf[bi][0][0];

    // QK^T swapped: s[kf][r] = S[kv = kf*16 + 4g + r][q = j]
    f32x4 s[4] = {};
    __builtin_amdgcn_s_setprio(1);
    #pragma unroll
    for (int kf = 0; kf < 4; ++kf){
      #pragma unroll
      for (int kb = 0; kb < 4; ++kb){
        int off = (kf * 16 + j) * 256 + kb * 64 + g * 16;
        off ^= ((j & 7) << 4);
        s[kf] = __builtin_amdgcn_mfma_f32_16x16x32_bf16(
                  *(const bf16x8*)(Kl + off), qreg[kb], s[kf], 0, 0, 0);
      }
    }
    __builtin_amdgcn_s_setprio(0);

    // online softmax for q-row j: in-lane over 16 + cross-g (lanes ^16, ^32)
    float pm = s[0][0];
    #pragma unroll
    for (int kf = 0; kf < 4; ++kf)
      #pragma unroll
      for (int r = 0; r < 4; ++r) pm = fmaxf(pm, s[kf][r]);
    pm = fmaxf(pm, __shfl_xor(pm, 16));
    pm = fmaxf(pm, __shfl_xor(pm, 32));
    int ok = (pm - m_ <= THR);
    if (!__all(ok)){
      float mn = fmaxf(m_, pm);
      float cf = exp2f(m_ - mn);
      m_ = mn;
      l_ *= cf;
      float cfr[4];
      #pragma unroll
      for (int r = 0; r < 4; ++r) cfr[r] = __shfl(cf, g * 4 + r);
      #pragma unroll
      for (int df = 0; df < 8; ++df)
        #pragma unroll
        for (int r = 0; r < 4; ++r) ctx[df][r] *= cfr[r];
    }
    float rs = 0.f;
    #pragma unroll
    for (int kf = 0; kf < 4; ++kf)
      #pragma unroll
      for (int r = 0; r < 4; ++r){ s[kf][r] = exp2f(s[kf][r] - m_); rs += s[kf][r]; }
    rs += __shfl_xor(rs, 16);
    rs += __shfl_xor(rs, 32);
    l_ += rs;

    // P -> bf16 A-frags, fully in-register (V columns pre-permuted to match)
    union { unsigned u[4]; bf16x8 v; } pa[2];
    #pragma unroll
    for (int kb = 0; kb < 2; ++kb){
      asm("v_cvt_pk_bf16_f32 %0, %1, %2" : "=v"(pa[kb].u[0]) : "v"(s[2*kb][0]),   "v"(s[2*kb][1]));
      asm("v_cvt_pk_bf16_f32 %0, %1, %2" : "=v"(pa[kb].u[1]) : "v"(s[2*kb][2]),   "v"(s[2*kb][3]));
      asm("v_cvt_pk_bf16_f32 %0, %1, %2" : "=v"(pa[kb].u[2]) : "v"(s[2*kb+1][0]), "v"(s[2*kb+1][1]));
      asm("v_cvt_pk_bf16_f32 %0, %1, %2" : "=v"(pa[kb].u[3]) : "v"(s[2*kb+1][2]), "v"(s[2*kb+1][3]));
    }

    // PV: ctx[df][r] = O[q = 4g+r][dv = df*16 + j]
    __builtin_amdgcn_s_setprio(1);
    #pragma unroll
    for (int df = 0; df < 8; ++df){
      int off0 = (df * 16 + j) * 128 + g * 16;        int o0 = off0 ^ ((j & 7) << 4);
      int off1 = (df * 16 + j) * 128 + 64 + g * 16;   int o1 = off1 ^ ((j & 7) << 4);
      ctx[df] = __builtin_amdgcn_mfma_f32_16x16x32_bf16(pa[0].v, *(const bf16x8*)(Vl + o0), ctx[df], 0, 0, 0);
      ctx[df] = __builtin_amdgcn_mfma_f32_16x16x32_bf16(pa[1].v, *(const bf16x8*)(Vl + o1), ctx[df], 0, 0, 0);
    }
    __builtin_amdgcn_s_setprio(0);
    __syncthreads();
  }

  size_t prow0 = ((size_t)sp * 32 + bh) * QL_ + qbase;
  #pragma unroll
  for (int r = 0; r < 4; ++r){
    float* cp = ctxp + (prow0 + g * 4 + r) * DH;
    #pragma unroll
    for (int df = 0; df < 8; ++df) cp[df * 16 + j] = ctx[df][r];
  }
  if (g == 0){
    mlp[(prow0 + j) * 2]     = m_;
    mlp[(prow0 + j) * 2 + 1] = l_;
  }
}

// ---------------- Split combine: 1 wave per q-row (m in log2 domain) ----------------
__global__ __launch_bounds__(256)
void combine_kernel(const float* __restrict__ ctxp, const float* __restrict__ mlp,
                    float* __restrict__ out){
  int row = blockIdx.x * 4 + (threadIdx.x >> 6);   // (b*8+h)*512 + q
  int lane = threadIdx.x & 63;
  int b = row >> 12, h = (row >> 9) & 7, q = row & 511;
  float ms[NS], ls[NS];
  #pragma unroll
  for (int s = 0; s < NS; ++s){
    ms[s] = mlp[((size_t)(s * NROWS + row)) * 2];
    ls[s] = mlp[((size_t)(s * NROWS + row)) * 2 + 1];
  }
  float M = ms[0];
  #pragma unroll
  for (int s = 1; s < NS; ++s) M = fmaxf(M, ms[s]);
  float wgt[NS], L = 0.f;
  #pragma unroll
  for (int s = 0; s < NS; ++s){ wgt[s] = exp2f(ms[s] - M); L += ls[s] * wgt[s]; }
  float inv = 1.f / L;
  float ax = 0.f, ay = 0.f;
  #pragma unroll
  for (int s = 0; s < NS; ++s){
    const float* cp = ctxp + ((size_t)(s * NROWS + row)) * DH + lane * 2;
    ax += cp[0] * wgt[s]; ay += cp[1] * wgt[s];
  }
  float* op = out + ((size_t)(b * QL_ + q)) * NCH + h * DH + lane * 2;
  op[0] = ax * inv; op[1] = ay * inv;
}

extern "C" void kernel_launch(void* const* d_in, const int* in_sizes, int n_in,
                              void* d_out, int out_size, void* d_ws, size_t ws_size,
                              hipStream_t stream){
  const float* hs   = (const float*)d_in[0];
  const float* inp  = (const float*)d_in[1];
  const float* ln1g = (const float*)d_in[2];
  const float* ln1b = (const float*)d_in[3];
  const float* ln2g = (const float*)d_in[4];
  const float* ln2b = (const float*)d_in[5];
  const float* Wq   = (const float*)d_in[6];
  const float* bq   = (const float*)d_in[7];
  const float* Wk   = (const float*)d_in[8];
  const float* bk   = (const float*)d_in[9];
  const float* Wv   = (const float*)d_in[10];
  const float* bv   = (const float*)d_in[11];

  char* ws = (char*)d_ws;
  size_t off = 0;
  auto alloc = [&](size_t bytes){ void* pp = ws + off; off += (bytes + 255) & ~255ull; return pp; };
  // persistent across phases
  ushort_t* Qm = (ushort_t*)alloc((size_t)2048 * 1024 * 2);
  ushort_t* Km = (ushort_t*)alloc((size_t)16384 * 1024 * 2);
  ushort_t* Vt = (ushort_t*)alloc((size_t)16384 * 1024 * 2);
  size_t base2 = off;
  // phase 1: LN outputs + transposed weights (dead after the GEMMs)
  ushort_t* hs_ln = (ushort_t*)alloc((size_t)2048 * 1024 * 2);
  ushort_t* in_ln = (ushort_t*)alloc((size_t)16384 * 768 * 2);
  ushort_t* Wqt   = (ushort_t*)alloc((size_t)1024 * 1024 * 2);
  ushort_t* Wkt   = (ushort_t*)alloc((size_t)1024 * 768 * 2);
  ushort_t* Wvt   = (ushort_t*)alloc((size_t)1024 * 768 * 2);
  // phase 2: attention partials (alias phase 1)
  off = base2;
  float* ctxp = (float*)alloc((size_t)NS * NROWS * DH * 4);
  float* mlp  = (float*)alloc((size_t)NS * NROWS * 2 * 4);

  const float QSC = 0.08838834764831845f * 1.4426950408889634f;  // 1/sqrt(128)*log2(e)

  ln_kernel<1024><<<2048, 256, 0, stream>>>(hs, ln1g, ln1b, hs_ln);
  ln_kernel<768><<<16384, 256, 0, stream>>>(inp, ln2g, ln2b, in_ln);
  wtrans_kernel<<<dim3(32, 32), 256, 0, stream>>>(Wq, Wqt, 1024, 1024);
  wtrans_kernel<<<dim3(32, 24), 256, 0, stream>>>(Wk, Wkt, 768, 1024);
  wtrans_kernel<<<dim3(32, 24), 256, 0, stream>>>(Wv, Wvt, 768, 1024);
  gemm_kernel<false><<<dim3(16, 8),  256, 0, stream>>>(hs_ln, Wqt, bq, Qm, 2048, 1024, QSC);
  gemm_kernel<false><<<dim3(128, 8), 256, 0, stream>>>(in_ln, Wkt, bk, Km, 16384, 768, 1.0f);
  gemm_kernel<true ><<<dim3(128, 8), 256, 0, stream>>>(in_ln, Wvt, bv, Vt, 16384, 768, 1.0f);
  attn_kernel<<<512, 512, 0, stream>>>(Qm, Km, Vt, ctxp, mlp);
  combine_kernel<<<NROWS / 4, 256, 0, stream>>>(ctxp, mlp, (float*)d_out);
}

// Round 9
// 175.278 us; speedup vs baseline: 2.7513x; 1.2490x over previous
//
#include <hip/hip_runtime.h>
#include <hip/hip_bf16.h>
#include <stdint.h>

#define B_    4
#define QL_   512
#define KVL_  4096
#define QDIM  1024
#define KVDIM 768
#define NCH   1024
#define H_    8
#define DH    128
#define NROWS (B_ * H_ * QL_)   // 16384 partial rows
#define KVBLK 64
#define NS    4

typedef unsigned short ushort_t;
typedef __attribute__((ext_vector_type(8))) short bf16x8;
typedef __attribute__((ext_vector_type(4))) float f32x4;
typedef __attribute__((ext_vector_type(4))) unsigned short us4;

__device__ __forceinline__ ushort_t f2bf(float x){
  union { float f; unsigned u; } v; v.f = x;
  unsigned r = v.u + 0x7FFF + ((v.u >> 16) & 1);
  return (ushort_t)(r >> 16);
}

__device__ __forceinline__ void gload16(void* l, const void* g){
  __builtin_amdgcn_global_load_lds(
    (const __attribute__((address_space(1))) unsigned int*)g,
    (__attribute__((address_space(3))) unsigned int*)l, 16, 0, 0);
}

// ---------------- LayerNorm + bf16 cast ----------------
template<int D>
__global__ void ln_kernel(const float* __restrict__ x, const float* __restrict__ gamma,
                          const float* __restrict__ beta, ushort_t* __restrict__ out){
  int row = blockIdx.x;
  const float* xr = x + (size_t)row * D;
  ushort_t* orow = out + (size_t)row * D;
  int tid = threadIdx.x;
  constexpr int NPT = D / 256;
  float v[NPT];
  float s = 0.f, s2 = 0.f;
  #pragma unroll
  for (int k = 0; k < NPT; ++k){ v[k] = xr[tid + k*256]; s += v[k]; s2 += v[k]*v[k]; }
  #pragma unroll
  for (int m = 32; m; m >>= 1){ s += __shfl_xor(s, m); s2 += __shfl_xor(s2, m); }
  __shared__ float red[8];
  int w = tid >> 6;
  if ((tid & 63) == 0){ red[w] = s; red[4 + w] = s2; }
  __syncthreads();
  s  = red[0] + red[1] + red[2] + red[3];
  s2 = red[4] + red[5] + red[6] + red[7];
  float mu  = s / D;
  float var = s2 / D - mu * mu;
  float rs  = rsqrtf(var + 1e-3f);
  #pragma unroll
  for (int k = 0; k < NPT; ++k){
    int i = tid + k*256;
    orow[i] = f2bf((v[k] - mu) * rs * gamma[i] + beta[i]);
  }
}

// ---------------- Weight transpose + bf16 cast: Wt[n][k] = W[k][n] ----------------
__global__ void wtrans_kernel(const float* __restrict__ W, ushort_t* __restrict__ Wt,
                              int K, int N){
  __shared__ float t[32][33];
  int n0 = blockIdx.x * 32, k0 = blockIdx.y * 32;
  int tx = threadIdx.x & 31, ty = threadIdx.x >> 5;   // 32 x 8
  #pragma unroll
  for (int i = 0; i < 32; i += 8) t[ty + i][tx] = W[(size_t)(k0 + ty + i) * N + n0 + tx];
  __syncthreads();
  #pragma unroll
  for (int i = 0; i < 32; i += 8)
    Wt[(size_t)(n0 + ty + i) * K + k0 + tx] = f2bf(t[tx][ty + i]);
}

// ---------------- small GEMM (Q): 128x128 tile, 3-buffer counted-vmcnt ----------------
__global__ __launch_bounds__(256)
void gemm_kernel(const ushort_t* __restrict__ A, const ushort_t* __restrict__ Bw,
                 const float* __restrict__ bias, ushort_t* __restrict__ out,
                 int M, int K, float oscale){
  __shared__ __align__(16) ushort_t lds[3][2][4][128][8];   // 48 KB, buf = ks%3
  int tid = threadIdx.x;
  int w = tid >> 6, lane = tid & 63;
  int m0 = blockIdx.x * 128, n0 = blockIdx.y * 128;
  int wr = w >> 1, wc = w & 1;
  int g = lane >> 4, j = lane & 15;
  f32x4 acc[4][4] = {};
  const int ksteps = K / 32;
  const ushort_t* Aw  = A  + (size_t)(m0 + lane) * K + w * 8;
  const ushort_t* Bww = Bw + (size_t)(n0 + lane) * K + w * 8;

  auto stage = [&](int buf, int ks){      // 4 loads/wave
    #pragma unroll
    for (int i = 0; i < 2; ++i){
      gload16(&lds[buf][0][w][i*64][0], Aw  + (size_t)i*64*K + ks*32);
      gload16(&lds[buf][1][w][i*64][0], Bww + (size_t)i*64*K + ks*32);
    }
  };

  stage(0, 0);
  stage(1, 1);
  asm volatile("s_waitcnt vmcnt(4)" ::: "memory");
  __builtin_amdgcn_s_barrier();
  __builtin_amdgcn_sched_barrier(0);

  int cur = 0;
  for (int ks = 0; ks < ksteps; ++ks){
    int nxt = cur + 2; if (nxt >= 3) nxt -= 3;
    bool pf = (ks + 2 < ksteps);
    if (pf) stage(nxt, ks + 2);
    bf16x8 af[4], bfr[4];
    #pragma unroll
    for (int mi = 0; mi < 4; ++mi) af[mi]  = *(const bf16x8*)&lds[cur][0][g][wr*64 + mi*16 + j][0];
    #pragma unroll
    for (int ni = 0; ni < 4; ++ni) bfr[ni] = *(const bf16x8*)&lds[cur][1][g][wc*64 + ni*16 + j][0];
    __builtin_amdgcn_s_setprio(1);
    #pragma unroll
    for (int mi = 0; mi < 4; ++mi)
      #pragma unroll
      for (int ni = 0; ni < 4; ++ni)
        acc[mi][ni] = __builtin_amdgcn_mfma_f32_16x16x32_bf16(af[mi], bfr[ni], acc[mi][ni], 0, 0, 0);
    __builtin_amdgcn_s_setprio(0);
    if (pf) asm volatile("s_waitcnt vmcnt(4)" ::: "memory");
    else    asm volatile("s_waitcnt vmcnt(0)" ::: "memory");
    __builtin_amdgcn_s_barrier();
    __builtin_amdgcn_sched_barrier(0);
    cur += 1; if (cur >= 3) cur -= 3;
  }

  #pragma unroll
  for (int mi = 0; mi < 4; ++mi){
    int row0 = m0 + wr*64 + mi*16 + g*4;
    #pragma unroll
    for (int ni = 0; ni < 4; ++ni){
      int col = n0 + wc*64 + ni*16 + j;
      float bs = bias[col];
      #pragma unroll
      for (int r = 0; r < 4; ++r)
        out[(size_t)(row0 + r) * NCH + col] = f2bf((acc[mi][ni][r] + bs) * oscale);
    }
  }
}

// ---------------- big GEMM (K/V): 256x256 tile, row-major LDS, coalesced staging ----------------
// LDS [3][2][256 rows][32 k] bf16 (96 KB). Staging: 4 lanes/row, 64B bursts (line-coalesced).
// Frag reads at stride 64B = 2-way bank alias (free). 8 waves (2Mx4N), 32 MFMA/wave/K-step.
// TRANSV: scatter into Vt[b][h][dv][c], c = PV A-frag column permutation of kv.
template<bool TRANSV>
__global__ __launch_bounds__(512, 2)
void gemm256_kernel(const ushort_t* __restrict__ A, const ushort_t* __restrict__ Bw,
                    const float* __restrict__ bias, ushort_t* __restrict__ out,
                    int M, int K, float oscale){
  __shared__ __align__(16) ushort_t lds[3][2][256][32];   // 96 KB, buf = ks%3
  int tid = threadIdx.x;
  int w = tid >> 6, lane = tid & 63;
  int m0 = blockIdx.x * 256, n0 = blockIdx.y * 256;
  int wr = w >> 2, wc = w & 3;
  int g = lane >> 4, j = lane & 15;
  f32x4 acc[8][4] = {};
  const int ksteps = K / 32;
  int srow = tid >> 2, scolb = (tid & 3) * 8;            // 4 lanes per row, 64B/row
  const ushort_t* Asrc = A  + (size_t)(m0 + srow) * K + scolb;
  const ushort_t* Bsrc = Bw + (size_t)(n0 + srow) * K + scolb;

  auto stage = [&](int buf, int ks){      // 4 gload16/thread
    char* la = (char*)&lds[buf][0][0][0] + tid * 16;
    char* lb = (char*)&lds[buf][1][0][0] + tid * 16;
    #pragma unroll
    for (int i = 0; i < 2; ++i){
      gload16(la + i*8192, Asrc + (size_t)(i*128)*K + ks*32);
      gload16(lb + i*8192, Bsrc + (size_t)(i*128)*K + ks*32);
    }
  };

  stage(0, 0);
  stage(1, 1);
  asm volatile("s_waitcnt vmcnt(4)" ::: "memory");
  __builtin_amdgcn_s_barrier();
  __builtin_amdgcn_sched_barrier(0);

  int cur = 0;
  for (int ks = 0; ks < ksteps; ++ks){
    int nxt = cur + 2; if (nxt >= 3) nxt -= 3;
    bool pf = (ks + 2 < ksteps);
    if (pf) stage(nxt, ks + 2);
    const char* La = (const char*)&lds[cur][0][0][0];
    const char* Lb = (const char*)&lds[cur][1][0][0];
    bf16x8 af[8], bfr[4];
    #pragma unroll
    for (int mi = 0; mi < 8; ++mi) af[mi]  = *(const bf16x8*)(La + ((wr*128 + mi*16 + j) << 6) + (g << 4));
    #pragma unroll
    for (int ni = 0; ni < 4; ++ni) bfr[ni] = *(const bf16x8*)(Lb + ((wc*64  + ni*16 + j) << 6) + (g << 4));
    __builtin_amdgcn_s_setprio(1);
    #pragma unroll
    for (int mi = 0; mi < 8; ++mi)
      #pragma unroll
      for (int ni = 0; ni < 4; ++ni)
        acc[mi][ni] = __builtin_amdgcn_mfma_f32_16x16x32_bf16(af[mi], bfr[ni], acc[mi][ni], 0, 0, 0);
    __builtin_amdgcn_s_setprio(0);
    if (pf) asm volatile("s_waitcnt vmcnt(4)" ::: "memory");
    else    asm volatile("s_waitcnt vmcnt(0)" ::: "memory");
    __builtin_amdgcn_s_barrier();
    __builtin_amdgcn_sched_barrier(0);
    cur += 1; if (cur >= 3) cur -= 3;
  }

  #pragma unroll
  for (int mi = 0; mi < 8; ++mi){
    int row0 = m0 + wr*128 + mi*16 + g*4;
    #pragma unroll
    for (int ni = 0; ni < 4; ++ni){
      int col = n0 + wc*64 + ni*16 + j;
      float bs = bias[col];
      if (!TRANSV){
        #pragma unroll
        for (int r = 0; r < 4; ++r)
          out[(size_t)(row0 + r) * NCH + col] = f2bf((acc[mi][ni][r] + bs) * oscale);
      } else {
        int bidx = row0 >> 12, kv = row0 & (KVL_ - 1);
        int h = col >> 7, dv = col & 127;
        int c = (kv & ~31) | (((kv & 15) >> 2) << 3) | (((kv >> 4) & 1) << 2);
        us4 pk;
        #pragma unroll
        for (int r = 0; r < 4; ++r) pk[r] = f2bf(acc[mi][ni][r] + bs);
        *(us4*)&out[((size_t)(bidx * H_ + h) * DH + dv) * KVL_ + c] = pk;
      }
    }
  }
}

// ---------------- Flash attention: swapped QK^T, in-register softmax ----------------
__global__ __launch_bounds__(512, 4)
void attn_kernel(const ushort_t* __restrict__ Q, const ushort_t* __restrict__ Km,
                 const ushort_t* __restrict__ Vt, float* __restrict__ ctxp,
                 float* __restrict__ mlp){
  __shared__ __align__(16) ushort_t Kbuf[2][KVBLK][DH];   // 32 KB
  __shared__ __align__(16) ushort_t Vbuf[2][DH][KVBLK];   // 32 KB (columns pre-permuted)

  int bid = blockIdx.x;
  int xcd = bid & 7, slot = bid >> 3;
  int p   = xcd + 8 * (slot >> 2);       // 0..127 -> (bh, sp)
  int qb  = slot & 3;
  int bh  = p >> 2, sp = p & 3;
  int b = bh >> 3, h = bh & 7;

  int tid = threadIdx.x;
  int w = tid >> 6, lane = tid & 63;
  int g = lane >> 4, j = lane & 15;
  int qbase = qb * 128 + w * 16;          // wave's 16 q-rows

  bf16x8 qreg[4];                          // Q[qbase+j][kb*32 + g*8 + e]
  {
    const ushort_t* Qb = Q + (size_t)(b * QL_ + qbase + j) * NCH + h * DH + g * 8;
    #pragma unroll
    for (int kb = 0; kb < 4; ++kb) qreg[kb] = *(const bf16x8*)(Qb + kb * 32);
  }

  f32x4 ctx[8] = {};
  float m_ = -1e30f, l_ = 0.f;

  const int kvbeg = sp * (KVL_ / NS);
  const char* Kg = (const char*)(Km + (size_t)b * KVL_ * NCH) + h * 256;
  const char* Vg = (const char*)(Vt + (size_t)(b * H_ + h) * DH * KVL_);

  auto stage = [&](int bi, int kv0){
    #pragma unroll
    for (int i = 0; i < 2; ++i){
      int lin = (i * 512 + tid) * 16;
      int sw  = lin ^ (((lin >> 8) & 7) << 4);
      gload16((char*)&Kbuf[bi][0][0] + lin,
              Kg + (size_t)(kv0 + (sw >> 8)) * 2048 + (sw & 255));
    }
    #pragma unroll
    for (int i = 0; i < 2; ++i){
      int lin = (i * 512 + tid) * 16;
      int sw  = lin ^ (((lin >> 7) & 7) << 4);
      gload16((char*)&Vbuf[bi][0][0] + lin,
              Vg + (size_t)(sw >> 7) * (KVL_ * 2) + kv0 * 2 + (sw & 127));
    }
  };

  const float THR = 11.5415603f;            // 8 * log2(e)
  const int NCHUNK = (KVL_ / NS) / KVBLK;   // 16

  stage(0, kvbeg);
  __syncthreads();

  for (int c = 0; c < NCHUNK; ++c){
    int bi = c & 1;
    if (c + 1 < NCHUNK) stage(bi ^ 1, kvbeg + (c + 1) * KVBLK);

    const char* Kl = (const char*)&Kbuf[bi][0][0];
    const char* Vl = (const char*)&Vbuf[bi][0][0];

    // QK^T swapped: s[kf][r] = S[kv = kf*16 + 4g + r][q = j]
    f32x4 s[4] = {};
    __builtin_amdgcn_s_setprio(1);
    #pragma unroll
    for (int kf = 0; kf < 4; ++kf){
      #pragma unroll
      for (int kb = 0; kb < 4; ++kb){
        int off = (kf * 16 + j) * 256 + kb * 64 + g * 16;
        off ^= ((j & 7) << 4);
        s[kf] = __builtin_amdgcn_mfma_f32_16x16x32_bf16(
                  *(const bf16x8*)(Kl + off), qreg[kb], s[kf], 0, 0, 0);
      }
    }
    __builtin_amdgcn_s_setprio(0);

    // online softmax for q-row j: in-lane over 16 + cross-g (lanes ^16, ^32)
    float pm = s[0][0];
    #pragma unroll
    for (int kf = 0; kf < 4; ++kf)
      #pragma unroll
      for (int r = 0; r < 4; ++r) pm = fmaxf(pm, s[kf][r]);
    pm = fmaxf(pm, __shfl_xor(pm, 16));
    pm = fmaxf(pm, __shfl_xor(pm, 32));
    int ok = (pm - m_ <= THR);
    if (!__all(ok)){
      float mn = fmaxf(m_, pm);
      float cf = exp2f(m_ - mn);
      m_ = mn;
      l_ *= cf;
      float cfr[4];
      #pragma unroll
      for (int r = 0; r < 4; ++r) cfr[r] = __shfl(cf, g * 4 + r);
      #pragma unroll
      for (int df = 0; df < 8; ++df)
        #pragma unroll
        for (int r = 0; r < 4; ++r) ctx[df][r] *= cfr[r];
    }
    float rs = 0.f;
    #pragma unroll
    for (int kf = 0; kf < 4; ++kf)
      #pragma unroll
      for (int r = 0; r < 4; ++r){ s[kf][r] = exp2f(s[kf][r] - m_); rs += s[kf][r]; }
    rs += __shfl_xor(rs, 16);
    rs += __shfl_xor(rs, 32);
    l_ += rs;

    // P -> bf16 A-frags, fully in-register (V columns pre-permuted to match)
    union { unsigned u[4]; bf16x8 v; } pa[2];
    #pragma unroll
    for (int kb = 0; kb < 2; ++kb){
      asm("v_cvt_pk_bf16_f32 %0, %1, %2" : "=v"(pa[kb].u[0]) : "v"(s[2*kb][0]),   "v"(s[2*kb][1]));
      asm("v_cvt_pk_bf16_f32 %0, %1, %2" : "=v"(pa[kb].u[1]) : "v"(s[2*kb][2]),   "v"(s[2*kb][3]));
      asm("v_cvt_pk_bf16_f32 %0, %1, %2" : "=v"(pa[kb].u[2]) : "v"(s[2*kb+1][0]), "v"(s[2*kb+1][1]));
      asm("v_cvt_pk_bf16_f32 %0, %1, %2" : "=v"(pa[kb].u[3]) : "v"(s[2*kb+1][2]), "v"(s[2*kb+1][3]));
    }

    // PV: ctx[df][r] = O[q = 4g+r][dv = df*16 + j]
    __builtin_amdgcn_s_setprio(1);
    #pragma unroll
    for (int df = 0; df < 8; ++df){
      int off0 = (df * 16 + j) * 128 + g * 16;        int o0 = off0 ^ ((j & 7) << 4);
      int off1 = (df * 16 + j) * 128 + 64 + g * 16;   int o1 = off1 ^ ((j & 7) << 4);
      ctx[df] = __builtin_amdgcn_mfma_f32_16x16x32_bf16(pa[0].v, *(const bf16x8*)(Vl + o0), ctx[df], 0, 0, 0);
      ctx[df] = __builtin_amdgcn_mfma_f32_16x16x32_bf16(pa[1].v, *(const bf16x8*)(Vl + o1), ctx[df], 0, 0, 0);
    }
    __builtin_amdgcn_s_setprio(0);
    __syncthreads();
  }

  size_t prow0 = ((size_t)sp * 32 + bh) * QL_ + qbase;
  #pragma unroll
  for (int r = 0; r < 4; ++r){
    float* cp = ctxp + (prow0 + g * 4 + r) * DH;
    #pragma unroll
    for (int df = 0; df < 8; ++df) cp[df * 16 + j] = ctx[df][r];
  }
  if (g == 0){
    mlp[(prow0 + j) * 2]     = m_;
    mlp[(prow0 + j) * 2 + 1] = l_;
  }
}

// ---------------- Split combine: 1 wave per q-row (m in log2 domain) ----------------
__global__ __launch_bounds__(256)
void combine_kernel(const float* __restrict__ ctxp, const float* __restrict__ mlp,
                    float* __restrict__ out){
  int row = blockIdx.x * 4 + (threadIdx.x >> 6);   // (b*8+h)*512 + q
  int lane = threadIdx.x & 63;
  int b = row >> 12, h = (row >> 9) & 7, q = row & 511;
  float ms[NS], ls[NS];
  #pragma unroll
  for (int s = 0; s < NS; ++s){
    ms[s] = mlp[((size_t)(s * NROWS + row)) * 2];
    ls[s] = mlp[((size_t)(s * NROWS + row)) * 2 + 1];
  }
  float M = ms[0];
  #pragma unroll
  for (int s = 1; s < NS; ++s) M = fmaxf(M, ms[s]);
  float wgt[NS], L = 0.f;
  #pragma unroll
  for (int s = 0; s < NS; ++s){ wgt[s] = exp2f(ms[s] - M); L += ls[s] * wgt[s]; }
  float inv = 1.f / L;
  float ax = 0.f, ay = 0.f;
  #pragma unroll
  for (int s = 0; s < NS; ++s){
    const float* cp = ctxp + ((size_t)(s * NROWS + row)) * DH + lane * 2;
    ax += cp[0] * wgt[s]; ay += cp[1] * wgt[s];
  }
  float* op = out + ((size_t)(b * QL_ + q)) * NCH + h * DH + lane * 2;
  op[0] = ax * inv; op[1] = ay * inv;
}

extern "C" void kernel_launch(void* const* d_in, const int* in_sizes, int n_in,
                              void* d_out, int out_size, void* d_ws, size_t ws_size,
                              hipStream_t stream){
  const float* hs   = (const float*)d_in[0];
  const float* inp  = (const float*)d_in[1];
  const float* ln1g = (const float*)d_in[2];
  const float* ln1b = (const float*)d_in[3];
  const float* ln2g = (const float*)d_in[4];
  const float* ln2b = (const float*)d_in[5];
  const float* Wq   = (const float*)d_in[6];
  const float* bq   = (const float*)d_in[7];
  const float* Wk   = (const float*)d_in[8];
  const float* bk   = (const float*)d_in[9];
  const float* Wv   = (const float*)d_in[10];
  const float* bv   = (const float*)d_in[11];

  char* ws = (char*)d_ws;
  size_t off = 0;
  auto alloc = [&](size_t bytes){ void* pp = ws + off; off += (bytes + 255) & ~255ull; return pp; };
  // persistent across phases
  ushort_t* Qm = (ushort_t*)alloc((size_t)2048 * 1024 * 2);
  ushort_t* Km = (ushort_t*)alloc((size_t)16384 * 1024 * 2);
  ushort_t* Vt = (ushort_t*)alloc((size_t)16384 * 1024 * 2);
  size_t base2 = off;
  // phase 1: LN outputs + transposed weights (dead after the GEMMs)
  ushort_t* hs_ln = (ushort_t*)alloc((size_t)2048 * 1024 * 2);
  ushort_t* in_ln = (ushort_t*)alloc((size_t)16384 * 768 * 2);
  ushort_t* Wqt   = (ushort_t*)alloc((size_t)1024 * 1024 * 2);
  ushort_t* Wkt   = (ushort_t*)alloc((size_t)1024 * 768 * 2);
  ushort_t* Wvt   = (ushort_t*)alloc((size_t)1024 * 768 * 2);
  // phase 2: attention partials (alias phase 1)
  off = base2;
  float* ctxp = (float*)alloc((size_t)NS * NROWS * DH * 4);
  float* mlp  = (float*)alloc((size_t)NS * NROWS * 2 * 4);

  const float QSC = 0.08838834764831845f * 1.4426950408889634f;  // 1/sqrt(128)*log2(e)

  ln_kernel<1024><<<2048, 256, 0, stream>>>(hs, ln1g, ln1b, hs_ln);
  ln_kernel<768><<<16384, 256, 0, stream>>>(inp, ln2g, ln2b, in_ln);
  wtrans_kernel<<<dim3(32, 32), 256, 0, stream>>>(Wq, Wqt, 1024, 1024);
  wtrans_kernel<<<dim3(32, 24), 256, 0, stream>>>(Wk, Wkt, 768, 1024);
  wtrans_kernel<<<dim3(32, 24), 256, 0, stream>>>(Wv, Wvt, 768, 1024);
  gemm_kernel<<<dim3(16, 8), 256, 0, stream>>>(hs_ln, Wqt, bq, Qm, 2048, 1024, QSC);
  gemm256_kernel<false><<<dim3(64, 4), 512, 0, stream>>>(in_ln, Wkt, bk, Km, 16384, 768, 1.0f);
  gemm256_kernel<true ><<<dim3(64, 4), 512, 0, stream>>>(in_ln, Wvt, bv, Vt, 16384, 768, 1.0f);
  attn_kernel<<<512, 512, 0, stream>>>(Qm, Km, Vt, ctxp, mlp);
  combine_kernel<<<NROWS / 4, 256, 0, stream>>>(ctxp, mlp, (float*)d_out);
}